// Round 8
// baseline (137.189 us; speedup 1.0000x reference)
//
#include <hip/hip_runtime.h>
#include <math.h>

#define NB 4
#define NN 256
#define MAT (NN*NN)      // 65536
#define BMAT (NB*MAT)    // 262144
#define ALPHA 0.2f

typedef __attribute__((ext_vector_type(8))) __bf16 bf16x8;
typedef __attribute__((ext_vector_type(4))) float f32x4;

union U8 { bf16x8 v; unsigned short u[8]; };

#define MFMA(acc, A, B) acc = __builtin_amdgcn_mfma_f32_16x16x32_bf16(A, B, acc, 0, 0, 0)

__device__ __forceinline__ unsigned short f2bf(float x) {
    unsigned u = __float_as_uint(x);
    u = (u + 0x7FFFu + ((u >> 16) & 1u)) >> 16;
    return (unsigned short)u;
}
__device__ __forceinline__ float bf2f(unsigned short h) {
    return __uint_as_float(((unsigned)h) << 16);
}
__device__ __forceinline__ void split3(float x, unsigned short& a,
                                       unsigned short& b, unsigned short& c) {
    a = f2bf(x); float r = x - bf2f(a);
    b = f2bf(r); r -= bf2f(b);
    c = f2bf(r);
}

__device__ __forceinline__ float wave_sum(float v) {
#pragma unroll
    for (int o = 32; o > 0; o >>= 1) v += __shfl_down(v, o, 64);
    return v;
}
__device__ __forceinline__ float block_sum256(float v, volatile float* red) {
    int lane = threadIdx.x & 63, w = threadIdx.x >> 6;
    v = wave_sum(v);
    __syncthreads();
    if (lane == 0) red[w] = v;
    __syncthreads();
    return red[0] + red[1] + red[2] + red[3];
}

// ---- k_pre: 2048 blocks. bid<1024: W split+transpose (4 matrices).
//            bid>=1024: E split into 3 bf16 planes (layer-0 input).
__global__ __launch_bounds__(256) void k_pre(
    const float* __restrict__ w0, const float* __restrict__ w1,
    const float* __restrict__ w2, const float* __restrict__ w3,
    const float* __restrict__ edges,
    unsigned short* __restrict__ WT, unsigned short* __restrict__ Epl)
{
    int bid = blockIdx.x, tid = threadIdx.x;
    if (bid < 1024) {
        int m = bid >> 8, k = bid & 255, j = tid;
        const float* Wm = (m == 0) ? w0 : (m == 1) ? w1 : (m == 2) ? w2 : w3;
        float x = Wm[k * NN + j];
        unsigned short s0, s1, s2; split3(x, s0, s1, s2);
        unsigned short* base = WT + m * 3 * MAT;
        base[0 * MAT + j * NN + k] = s0;
        base[1 * MAT + j * NN + k] = s1;
        base[2 * MAT + j * NN + k] = s2;
    } else {
        int idx = (bid - 1024) * 256 + tid;
        unsigned short s0, s1, s2; split3(edges[idx], s0, s1, s2);
        Epl[idx] = s0; Epl[BMAT + idx] = s1; Epl[2 * BMAT + idx] = s2;
    }
}

// ---- Kernel A: per 8-row panel, compute Grow=(E@wa)[rows,:], Gt=(E@wa)[:,rows]^T,
// H=(E@wp)[rows,:] (all 6-term compensated, matched accumulation order);
// then adjacency + row stats + eL/eH 3-split planes, each computed once.
// grid 128 = (4 b) x (32 panels), 256 threads (4 waves; wave w owns 64 cols).
__global__ __launch_bounds__(256) void k_ghprep(
    const unsigned short* __restrict__ Epl,
    const unsigned short* __restrict__ WTa, const float* __restrict__ ba,
    const unsigned short* __restrict__ WTp, const float* __restrict__ bp,
    const float* __restrict__ ae,
    unsigned short* __restrict__ adjb,
    unsigned short* __restrict__ eLp, unsigned short* __restrict__ eHp,
    float* __restrict__ cnt, float* __restrict__ rs)
{
    __shared__ float red[4];
    __shared__ float sAdj[8 * 256];
    __shared__ float sH[8 * 256];

    int bid = blockIdx.x;
    int b = bid >> 5, p = bid & 31;
    int r0 = p * 8;
    int t = threadIdx.x;
    float S = block_sum256(ae[t] + ae[t + 256], red);

    int w = t >> 6, lane = t & 63, l15 = lane & 15, lk = (lane >> 4) * 8;
    int ar = r0 + (l15 & 7);          // dup rows 8..15 -> 0..7 (M=16 pad)

    f32x4 gR[4], gT[4], hA[4];
#pragma unroll
    for (int ct = 0; ct < 4; ++ct) { gR[ct] = 0.f; gT[ct] = 0.f; hA[ct] = 0.f; }

    int aEbase = b * MAT + ar * NN;
    int aWbase = ar * NN;
    for (int k0 = 0; k0 < NN; k0 += 32) {
        int kb = k0 + lk;
        U8 aE[3], aW[3];
#pragma unroll
        for (int pp = 0; pp < 3; ++pp) {
            aE[pp].v = *(const bf16x8*)&Epl[pp * BMAT + aEbase + kb];
            aW[pp].v = *(const bf16x8*)&WTa[pp * MAT + aWbase + kb];
        }
#pragma unroll
        for (int ct = 0; ct < 4; ++ct) {
            int j0 = (w * 64 + ct * 16 + l15) * NN;
            U8 bW[3], bE[3], bP[3];
#pragma unroll
            for (int pp = 0; pp < 3; ++pp) {
                bW[pp].v = *(const bf16x8*)&WTa[pp * MAT + j0 + kb];
                bE[pp].v = *(const bf16x8*)&Epl[pp * BMAT + b * MAT + j0 + kb];
                bP[pp].v = *(const bf16x8*)&WTp[pp * MAT + j0 + kb];
            }
            // Grow: 6-term, (E,W) order (0,0)(0,1)(1,0)(0,2)(1,1)(2,0)
            MFMA(gR[ct], aE[0].v, bW[0].v);
            MFMA(gR[ct], aE[0].v, bW[1].v); MFMA(gR[ct], aE[1].v, bW[0].v);
            MFMA(gR[ct], aE[0].v, bW[2].v); MFMA(gR[ct], aE[1].v, bW[1].v);
            MFMA(gR[ct], aE[2].v, bW[0].v);
            // Gt: 6-term with the SAME (E,W) accumulation order, so panel(i)
            // and panel(j) compute bit-consistent g1+g2 for each pair.
            MFMA(gT[ct], aW[0].v, bE[0].v);   // E0W0
            MFMA(gT[ct], aW[1].v, bE[0].v);   // E0W1
            MFMA(gT[ct], aW[0].v, bE[1].v);   // E1W0
            MFMA(gT[ct], aW[2].v, bE[0].v);   // E0W2
            MFMA(gT[ct], aW[1].v, bE[1].v);   // E1W1
            MFMA(gT[ct], aW[0].v, bE[2].v);   // E2W0
            // H: 6-term
            MFMA(hA[ct], aE[0].v, bP[0].v);
            MFMA(hA[ct], aE[0].v, bP[1].v); MFMA(hA[ct], aE[1].v, bP[0].v);
            MFMA(hA[ct], aE[0].v, bP[2].v); MFMA(hA[ct], aE[1].v, bP[1].v);
            MFMA(hA[ct], aE[2].v, bP[0].v);
        }
    }

    // panel rows 0..7 -> LDS (lanes whose C rows are the non-dup copies)
    int g = lane >> 4;
    if (g < 2) {
#pragma unroll
        for (int ct = 0; ct < 4; ++ct) {
            int j = w * 64 + ct * 16 + l15;
            float baj = ba[j], bpj = bp[j];
#pragma unroll
            for (int r = 0; r < 4; ++r) {
                int m = g * 4 + r;     // 0..7
                float adjv = (gR[ct][r] + gT[ct][r] + baj + ba[r0 + m] > 0.f) ? 1.f : 0.f;
                sAdj[m * 256 + j] = adjv;
                sH[m * 256 + j] = hA[ct][r] + bpj;
            }
        }
    }
    __syncthreads();

    // stats + emit: 32 threads per row
    int r = t >> 5, c8 = (t & 31) * 8;
    float hv[8], av[8];
    float cntp = 0.f, hsum = 0.f, lmax = -3.4e38f;
#pragma unroll
    for (int i = 0; i < 8; ++i) {
        float h = sH[r * 256 + c8 + i];
        float a = sAdj[r * 256 + c8 + i];
        hv[i] = h; av[i] = a;
        cntp += a; hsum += h;
        float x = S * h;
        lmax = fmaxf(lmax, (x > 0.f) ? x : ALPHA * x);
    }
#pragma unroll
    for (int o = 1; o < 32; o <<= 1) {
        cntp += __shfl_xor(cntp, o, 64);
        hsum += __shfl_xor(hsum, o, 64);
        lmax = fmaxf(lmax, __shfl_xor(lmax, o, 64));
    }
    int orow = b * NN + r0 + r;
    if ((t & 31) == 0) { cnt[orow] = cntp; rs[orow] = hsum; }

    int obase = b * MAT + (r0 + r) * NN + c8;
    U8 e0, e1, e2, q0, q1, q2, ad;
#pragma unroll
    for (int i = 0; i < 8; ++i) {
        float x = S * hv[i];
        float L = (x > 0.f) ? x : ALPHA * x;
        float e = __expf(L - lmax);
        float eh = e * hv[i];
        split3(e,  e0.u[i], e1.u[i], e2.u[i]);
        split3(eh, q0.u[i], q1.u[i], q2.u[i]);
        ad.u[i] = f2bf(av[i]);
    }
    *(bf16x8*)&eLp[obase]            = e0.v;
    *(bf16x8*)&eLp[BMAT + obase]     = e1.v;
    *(bf16x8*)&eLp[2 * BMAT + obase] = e2.v;
    *(bf16x8*)&eHp[obase]            = q0.v;
    *(bf16x8*)&eHp[BMAT + obase]     = q1.v;
    *(bf16x8*)&eHp[2 * BMAT + obase] = q2.v;
    *(bf16x8*)&adjb[obase]           = ad.v;
}

// ---- Kernel B: D/N GEMM pair + divide/fallback + symmetrize (+tanh / E-split).
// grid (136, NB) x 128: 2 waves = 2 sides of pair (ti,tj), direct global reads.
template<int FINAL>
__global__ __launch_bounds__(128) void k_fs(
    const unsigned short* __restrict__ eLp, const unsigned short* __restrict__ eHp,
    const unsigned short* __restrict__ adjb,
    const float* __restrict__ cnt, const float* __restrict__ rs,
    unsigned short* __restrict__ Epl, float* __restrict__ out)
{
    __shared__ float Fs[2][16 * 17];
    int b = blockIdx.y;
    int ti = 0, rem = blockIdx.x;
    while (rem >= 16 - ti) { rem -= 16 - ti; ++ti; }
    int tj = ti + rem;
    int t = threadIdx.x, s = t >> 6, lane = t & 63, l15 = lane & 15, lk = (lane >> 4) * 8;
    int R = s ? tj : ti, C = s ? ti : tj;
    int arow = b * MAT + (R * 16 + l15) * NN;
    int brow = b * MAT + (C * 16 + l15) * NN;

    f32x4 aD = 0.f, aN = 0.f;
    for (int k0 = 0; k0 < NN; k0 += 32) {
        int kv = k0 + lk;
        bf16x8 L0 = *(const bf16x8*)&eLp[arow + kv];
        bf16x8 L1 = *(const bf16x8*)&eLp[BMAT + arow + kv];
        bf16x8 L2 = *(const bf16x8*)&eLp[2 * BMAT + arow + kv];
        bf16x8 H0 = *(const bf16x8*)&eHp[arow + kv];
        bf16x8 H1 = *(const bf16x8*)&eHp[BMAT + arow + kv];
        bf16x8 H2 = *(const bf16x8*)&eHp[2 * BMAT + arow + kv];
        bf16x8 Av = *(const bf16x8*)&adjb[brow + kv];
        MFMA(aD, L0, Av); MFMA(aD, L1, Av); MFMA(aD, L2, Av);
        MFMA(aN, H0, Av); MFMA(aN, H1, Av); MFMA(aN, H2, Av);
    }

    int colA = C * 16 + l15;
    float cA = cnt[b * NN + colA];
    float F[4];
#pragma unroll
    for (int r = 0; r < 4; ++r) {
        int m = (lane >> 4) * 4 + r;
        F[r] = (cA > 0.5f) ? aN[r] / aD[r]
                           : rs[b * NN + R * 16 + m] * (1.f / 256.f);
        Fs[s][m * 17 + l15] = F[r];
    }
    __syncthreads();
#pragma unroll
    for (int r = 0; r < 4; ++r) {
        int m = (lane >> 4) * 4 + r;
        float e = 0.5f * (F[r] + Fs[1 ^ s][l15 * 17 + m]);
        int idx = b * MAT + (R * 16 + m) * NN + C * 16 + l15;
        if (FINAL) {
            float tv = tanhf(e);
            out[idx] = tv; out[BMAT + idx] = tv;
        } else {
            unsigned short s0, s1, s2;
            split3(e, s0, s1, s2);
            Epl[idx] = s0; Epl[BMAT + idx] = s1; Epl[2 * BMAT + idx] = s2;
        }
    }
}

extern "C" void kernel_launch(void* const* d_in, const int* in_sizes, int n_in,
                              void* d_out, int out_size, void* d_ws, size_t ws_size,
                              hipStream_t stream) {
    const float* edges = (const float*)d_in[1];
    const float* wp[2] = {(const float*)d_in[7],  (const float*)d_in[17]};
    const float* bp[2] = {(const float*)d_in[8],  (const float*)d_in[18]};
    const float* ae[2] = {(const float*)d_in[9],  (const float*)d_in[19]};
    const float* wa[2] = {(const float*)d_in[10], (const float*)d_in[20]};
    const float* ba[2] = {(const float*)d_in[11], (const float*)d_in[21]};
    float* out = (float*)d_out;

    // ws layout (~8.4 MB)
    unsigned short* WT   = (unsigned short*)d_ws;   // 12 planes * 128KB
    unsigned short* EplA = WT + 12 * MAT;           // 3 planes
    unsigned short* EplB = EplA + 3 * BMAT;         // 3 planes
    unsigned short* adjb = EplB + 3 * BMAT;         // 1 plane
    unsigned short* eLp  = adjb + BMAT;             // 3 planes
    unsigned short* eHp  = eLp + 3 * BMAT;          // 3 planes
    float* cnt = (float*)(eHp + 3 * BMAT);          // 4KB
    float* rs  = cnt + NB * NN;                     // 4KB

    k_pre<<<2048, 256, 0, stream>>>(wa[0], wp[0], wa[1], wp[1], edges, WT, EplA);

    for (int l = 0; l < 2; ++l) {
        const unsigned short* WTa = WT + (l * 2 + 0) * 3 * MAT;
        const unsigned short* WTp = WT + (l * 2 + 1) * 3 * MAT;
        const unsigned short* Ein = l ? EplB : EplA;
        k_ghprep<<<128, 256, 0, stream>>>(Ein, WTa, ba[l], WTp, bp[l], ae[l],
                                          adjb, eLp, eHp, cnt, rs);
        if (l == 0)
            k_fs<0><<<dim3(136, NB), 128, 0, stream>>>(eLp, eHp, adjb, cnt, rs,
                                                       EplB, nullptr);
        else
            k_fs<1><<<dim3(136, NB), 128, 0, stream>>>(eLp, eHp, adjb, cnt, rs,
                                                       nullptr, out);
    }
}

// Round 9
// 69.734 us; speedup vs baseline: 1.9673x; 1.9673x over previous
//
#include <hip/hip_runtime.h>
#include <math.h>

#define NB 4
#define NN 256
#define MAT (NN*NN)      // 65536
#define BMAT (NB*MAT)    // 262144
#define ALPHA 0.2f

typedef __attribute__((ext_vector_type(8))) __bf16 bf16x8;
typedef __attribute__((ext_vector_type(4))) float f32x4;
typedef __attribute__((ext_vector_type(4))) unsigned short u16x4;

union U8 { bf16x8 v; unsigned short u[8]; };

#define MFMA(acc, A, B) acc = __builtin_amdgcn_mfma_f32_16x16x32_bf16(A, B, acc, 0, 0, 0)

__device__ __forceinline__ unsigned short f2bf(float x) {
    unsigned u = __float_as_uint(x);
    u = (u + 0x7FFFu + ((u >> 16) & 1u)) >> 16;
    return (unsigned short)u;
}
__device__ __forceinline__ float bf2f(unsigned short h) {
    return __uint_as_float(((unsigned)h) << 16);
}
__device__ __forceinline__ void split3(float x, unsigned short& a,
                                       unsigned short& b, unsigned short& c) {
    a = f2bf(x); float r = x - bf2f(a);
    b = f2bf(r); r -= bf2f(b);
    c = f2bf(r);
}

__device__ __forceinline__ float wave_allsum(float v) {
#pragma unroll
    for (int o = 1; o < 64; o <<= 1) v += __shfl_xor(v, o, 64);
    return v;
}
__device__ __forceinline__ float wave_allmax(float v) {
#pragma unroll
    for (int o = 1; o < 64; o <<= 1) v = fmaxf(v, __shfl_xor(v, o, 64));
    return v;
}

// ---- k_pre: 2048 blocks. bid<1024: W split+transpose (4 matrices).
//            bid>=1024: E split into 3 bf16 planes (layer-0 input).
__global__ __launch_bounds__(256) void k_pre(
    const float* __restrict__ w0, const float* __restrict__ w1,
    const float* __restrict__ w2, const float* __restrict__ w3,
    const float* __restrict__ edges,
    unsigned short* __restrict__ WT, unsigned short* __restrict__ Epl)
{
    int bid = blockIdx.x, tid = threadIdx.x;
    if (bid < 1024) {
        int m = bid >> 8, k = bid & 255, j = tid;
        const float* Wm = (m == 0) ? w0 : (m == 1) ? w1 : (m == 2) ? w2 : w3;
        float x = Wm[k * NN + j];
        unsigned short s0, s1, s2; split3(x, s0, s1, s2);
        unsigned short* base = WT + m * 3 * MAT;
        base[0 * MAT + j * NN + k] = s0;
        base[1 * MAT + j * NN + k] = s1;
        base[2 * MAT + j * NN + k] = s2;
    } else {
        int idx = (bid - 1024) * 256 + tid;
        unsigned short s0, s1, s2; split3(edges[idx], s0, s1, s2);
        Epl[idx] = s0; Epl[BMAT + idx] = s1; Epl[2 * BMAT + idx] = s2;
    }
}

// ---- k_gh: G = E@wa+ba (+ GT transposed store), H = E@wp+bp.
// 1024 one-wave blocks, 16x32 tiles. GT[j,i] is G's own accumulator ->
// bit-identical, so adjacency threshold g1+g2>0 is exact-consistent.
__global__ __launch_bounds__(64) void k_gh(
    const unsigned short* __restrict__ Epl,
    const unsigned short* __restrict__ WTa, const float* __restrict__ ba,
    const unsigned short* __restrict__ WTp, const float* __restrict__ bp,
    float* __restrict__ G, float* __restrict__ GT, float* __restrict__ H)
{
    int bid = blockIdx.x;
    int m = bid >> 9, b = (bid >> 7) & 3, t = bid & 127;
    int tm = t >> 3, tn = t & 7;
    const unsigned short* WT = m ? WTp : WTa;
    const float* bias = m ? bp : ba;
    float* C = (m ? H : G) + b * MAT;
    int l = threadIdx.x, l15 = l & 15, lk = (l >> 4) * 8, lk4 = l >> 4;

    f32x4 acc[2]; acc[0] = 0.0f; acc[1] = 0.0f;
    int arow = b * MAT + (tm * 16 + l15) * NN;
    int col0 = (tn * 32 + l15) * NN, col1 = (tn * 32 + 16 + l15) * NN;

    const int TP[6] = {0, 0, 1, 0, 1, 2}, TQ[6] = {0, 1, 0, 2, 1, 0};
#pragma unroll
    for (int k0 = 0; k0 < NN; k0 += 32) {
        int kb = k0 + lk;
        U8 aE[3], wv[3][2];
#pragma unroll
        for (int pp = 0; pp < 3; ++pp) {
            aE[pp].v = *(const bf16x8*)&Epl[pp * BMAT + arow + kb];
            wv[pp][0].v = *(const bf16x8*)&WT[pp * MAT + col0 + kb];
            wv[pp][1].v = *(const bf16x8*)&WT[pp * MAT + col1 + kb];
        }
#pragma unroll
        for (int t6 = 0; t6 < 6; ++t6)
#pragma unroll
            for (int cg = 0; cg < 2; ++cg)
                MFMA(acc[cg], aE[TP[t6]].v, wv[TQ[t6]][cg].v);
    }
#pragma unroll
    for (int cg = 0; cg < 2; ++cg) {
        int col = tn * 32 + cg * 16 + l15;
        float bv = bias[col];
#pragma unroll
        for (int r = 0; r < 4; ++r) {
            int row = tm * 16 + lk4 * 4 + r;
            C[row * NN + col] = acc[cg][r] + bv;
        }
        if (m == 0) {   // transposed store of (acc+bias) into GT, 16B/lane
            f32x4 tv;
#pragma unroll
            for (int r = 0; r < 4; ++r) tv[r] = acc[cg][r] + bv;
            *(f32x4*)&GT[b * MAT + col * NN + tm * 16 + lk4 * 4] = tv;
        }
    }
}

// ---- k_prep: one WAVE per row. grid (NN, NB) x 64. No __syncthreads.
// Coalesced f32x4 row reads of G/GT/H; wave-allreduce stats; bf16x4 stores.
__global__ __launch_bounds__(64) void k_prep(
    const float* __restrict__ G, const float* __restrict__ GT,
    const float* __restrict__ H, const float* __restrict__ ae,
    unsigned short* __restrict__ adjb,
    unsigned short* __restrict__ eLp, unsigned short* __restrict__ eHp,
    float* __restrict__ cnt, float* __restrict__ rs)
{
    int i = blockIdx.x, b = blockIdx.y, lane = threadIdx.x;

    float sv = 0.f;
#pragma unroll
    for (int q = 0; q < 8; ++q) sv += ae[lane + 64 * q];
    float S = wave_allsum(sv);

    int base = b * MAT + i * NN + lane * 4;
    f32x4 gv = *(const f32x4*)&G[base];
    f32x4 gt = *(const f32x4*)&GT[base];
    f32x4 hv = *(const f32x4*)&H[base];

    float av[4], Lv[4];
    float cntp = 0.f, hsum = 0.f, lmax = -3.4e38f;
#pragma unroll
    for (int q = 0; q < 4; ++q) {
        av[q] = (gv[q] + gt[q] > 0.f) ? 1.f : 0.f;
        cntp += av[q];
        hsum += hv[q];
        float x = S * hv[q];
        Lv[q] = (x > 0.f) ? x : ALPHA * x;
        lmax = fmaxf(lmax, Lv[q]);
    }
    cntp = wave_allsum(cntp);
    hsum = wave_allsum(hsum);
    lmax = wave_allmax(lmax);
    if (lane == 0) { cnt[b * NN + i] = cntp; rs[b * NN + i] = hsum; }

    u16x4 e0, e1, e2, q0, q1, q2, ad;
#pragma unroll
    for (int q = 0; q < 4; ++q) {
        float e = __expf(Lv[q] - lmax);
        float eh = e * hv[q];
        unsigned short a_, b_, c_;
        split3(e, a_, b_, c_);  e0[q] = a_; e1[q] = b_; e2[q] = c_;
        split3(eh, a_, b_, c_); q0[q] = a_; q1[q] = b_; q2[q] = c_;
        ad[q] = f2bf(av[q]);
    }
    *(u16x4*)&adjb[base]           = ad;
    *(u16x4*)&eLp[base]            = e0;
    *(u16x4*)&eLp[BMAT + base]     = e1;
    *(u16x4*)&eLp[2 * BMAT + base] = e2;
    *(u16x4*)&eHp[base]            = q0;
    *(u16x4*)&eHp[BMAT + base]     = q1;
    *(u16x4*)&eHp[2 * BMAT + base] = q2;
}

// ---- Kernel B: D/N GEMM pair + divide/fallback + symmetrize (+tanh / E-split).
// grid (136, NB) x 128: 2 waves = 2 sides of pair (ti,tj), direct global reads.
template<int FINAL>
__global__ __launch_bounds__(128) void k_fs(
    const unsigned short* __restrict__ eLp, const unsigned short* __restrict__ eHp,
    const unsigned short* __restrict__ adjb,
    const float* __restrict__ cnt, const float* __restrict__ rs,
    unsigned short* __restrict__ Epl, float* __restrict__ out)
{
    __shared__ float Fs[2][16 * 17];
    int b = blockIdx.y;
    int ti = 0, rem = blockIdx.x;
    while (rem >= 16 - ti) { rem -= 16 - ti; ++ti; }
    int tj = ti + rem;
    int t = threadIdx.x, s = t >> 6, lane = t & 63, l15 = lane & 15, lk = (lane >> 4) * 8;
    int R = s ? tj : ti, C = s ? ti : tj;
    int arow = b * MAT + (R * 16 + l15) * NN;
    int brow = b * MAT + (C * 16 + l15) * NN;

    f32x4 aD = 0.f, aN = 0.f;
#pragma unroll
    for (int k0 = 0; k0 < NN; k0 += 32) {
        int kv = k0 + lk;
        bf16x8 L0 = *(const bf16x8*)&eLp[arow + kv];
        bf16x8 L1 = *(const bf16x8*)&eLp[BMAT + arow + kv];
        bf16x8 L2 = *(const bf16x8*)&eLp[2 * BMAT + arow + kv];
        bf16x8 H0 = *(const bf16x8*)&eHp[arow + kv];
        bf16x8 H1 = *(const bf16x8*)&eHp[BMAT + arow + kv];
        bf16x8 H2 = *(const bf16x8*)&eHp[2 * BMAT + arow + kv];
        bf16x8 Av = *(const bf16x8*)&adjb[brow + kv];
        MFMA(aD, L0, Av); MFMA(aD, L1, Av); MFMA(aD, L2, Av);
        MFMA(aN, H0, Av); MFMA(aN, H1, Av); MFMA(aN, H2, Av);
    }

    int colA = C * 16 + l15;
    float cA = cnt[b * NN + colA];
    float F[4];
#pragma unroll
    for (int r = 0; r < 4; ++r) {
        int m = (lane >> 4) * 4 + r;
        F[r] = (cA > 0.5f) ? aN[r] / aD[r]
                           : rs[b * NN + R * 16 + m] * (1.f / 256.f);
        Fs[s][m * 17 + l15] = F[r];
    }
    __syncthreads();
#pragma unroll
    for (int r = 0; r < 4; ++r) {
        int m = (lane >> 4) * 4 + r;
        float e = 0.5f * (F[r] + Fs[1 ^ s][l15 * 17 + m]);
        int idx = b * MAT + (R * 16 + m) * NN + C * 16 + l15;
        if (FINAL) {
            float tv = tanhf(e);
            out[idx] = tv; out[BMAT + idx] = tv;
        } else {
            unsigned short s0, s1, s2;
            split3(e, s0, s1, s2);
            Epl[idx] = s0; Epl[BMAT + idx] = s1; Epl[2 * BMAT + idx] = s2;
        }
    }
}

extern "C" void kernel_launch(void* const* d_in, const int* in_sizes, int n_in,
                              void* d_out, int out_size, void* d_ws, size_t ws_size,
                              hipStream_t stream) {
    const float* edges = (const float*)d_in[1];
    const float* wp[2] = {(const float*)d_in[7],  (const float*)d_in[17]};
    const float* bp[2] = {(const float*)d_in[8],  (const float*)d_in[18]};
    const float* ae[2] = {(const float*)d_in[9],  (const float*)d_in[19]};
    const float* wa[2] = {(const float*)d_in[10], (const float*)d_in[20]};
    const float* ba[2] = {(const float*)d_in[11], (const float*)d_in[21]};
    float* out = (float*)d_out;

    // ws layout (~11.4 MB)
    unsigned short* WT   = (unsigned short*)d_ws;   // 12 planes * 128KB
    unsigned short* EplA = WT + 12 * MAT;           // 3 planes
    unsigned short* EplB = EplA + 3 * BMAT;         // 3 planes
    unsigned short* adjb = EplB + 3 * BMAT;         // 1 plane
    unsigned short* eLp  = adjb + BMAT;             // 3 planes
    unsigned short* eHp  = eLp + 3 * BMAT;          // 3 planes
    float* G  = (float*)(eHp + 3 * BMAT);           // 1MB
    float* GT = G + BMAT;                           // 1MB
    float* H  = GT + BMAT;                          // 1MB
    float* cnt = H + BMAT;                          // 4KB
    float* rs  = cnt + NB * NN;                     // 4KB

    k_pre<<<2048, 256, 0, stream>>>(wa[0], wp[0], wa[1], wp[1], edges, WT, EplA);

    for (int l = 0; l < 2; ++l) {
        const unsigned short* WTa = WT + (l * 2 + 0) * 3 * MAT;
        const unsigned short* WTp = WT + (l * 2 + 1) * 3 * MAT;
        const unsigned short* Ein = l ? EplB : EplA;
        k_gh<<<1024, 64, 0, stream>>>(Ein, WTa, ba[l], WTp, bp[l], G, GT, H);
        k_prep<<<dim3(NN, NB), 64, 0, stream>>>(G, GT, H, ae[l], adjb, eLp, eHp, cnt, rs);
        if (l == 0)
            k_fs<0><<<dim3(136, NB), 128, 0, stream>>>(eLp, eHp, adjb, cnt, rs,
                                                       EplB, nullptr);
        else
            k_fs<1><<<dim3(136, NB), 128, 0, stream>>>(eLp, eHp, adjb, cnt, rs,
                                                       nullptr, out);
    }
}

// Round 10
// 67.053 us; speedup vs baseline: 2.0460x; 1.0400x over previous
//
#include <hip/hip_runtime.h>
#include <math.h>

#define NB 4
#define NN 256
#define MAT (NN*NN)      // 65536
#define BMAT (NB*MAT)    // 262144
#define ALPHA 0.2f

typedef __attribute__((ext_vector_type(8))) __bf16 bf16x8;
typedef __attribute__((ext_vector_type(4))) float f32x4;

union U8 { bf16x8 v; unsigned short u[8]; };

#define MFMA(acc, A, B) acc = __builtin_amdgcn_mfma_f32_16x16x32_bf16(A, B, acc, 0, 0, 0)

__device__ __forceinline__ unsigned short f2bf(float x) {
    unsigned u = __float_as_uint(x);
    u = (u + 0x7FFFu + ((u >> 16) & 1u)) >> 16;
    return (unsigned short)u;
}
__device__ __forceinline__ float bf2f(unsigned short h) {
    return __uint_as_float(((unsigned)h) << 16);
}
__device__ __forceinline__ void split3(float x, unsigned short& a,
                                       unsigned short& b, unsigned short& c) {
    a = f2bf(x); float r = x - bf2f(a);
    b = f2bf(r); r -= bf2f(b);
    c = f2bf(r);
}

__device__ __forceinline__ float wave_allsum(float v) {
#pragma unroll
    for (int o = 1; o < 64; o <<= 1) v += __shfl_xor(v, o, 64);
    return v;
}

// ---- k_pre: 1280 blocks.
// bid<256: W split+transpose via LDS 32x32 tile (coalesced 64B plane writes).
// bid>=256: E split into 3 bf16 planes (layer-0 input).
__global__ __launch_bounds__(256) void k_pre(
    const float* __restrict__ w0, const float* __restrict__ w1,
    const float* __restrict__ w2, const float* __restrict__ w3,
    const float* __restrict__ edges,
    unsigned short* __restrict__ WT, unsigned short* __restrict__ Epl)
{
    int bid = blockIdx.x, tid = threadIdx.x;
    if (bid < 256) {
        __shared__ float Ws[32][33];
        int m = bid >> 6, tile = bid & 63;
        int k0 = (tile >> 3) * 32, j0 = (tile & 7) * 32;
        const float* Wm = (m == 0) ? w0 : (m == 1) ? w1 : (m == 2) ? w2 : w3;
        int r = tid >> 5, c = tid & 31;
#pragma unroll
        for (int p4 = 0; p4 < 4; ++p4)
            Ws[r + 8 * p4][c] = Wm[(k0 + r + 8 * p4) * NN + j0 + c];
        __syncthreads();
        unsigned short* base = WT + m * 3 * MAT;
#pragma unroll
        for (int p4 = 0; p4 < 4; ++p4) {
            int jr = r + 8 * p4;
            unsigned short s0, s1, s2;
            split3(Ws[c][jr], s0, s1, s2);
            int o = (j0 + jr) * NN + k0 + c;
            base[o] = s0; base[MAT + o] = s1; base[2 * MAT + o] = s2;
        }
    } else {
        int idx = (bid - 256) * 256 + tid;
        unsigned short s0, s1, s2; split3(edges[idx], s0, s1, s2);
        Epl[idx] = s0; Epl[BMAT + idx] = s1; Epl[2 * BMAT + idx] = s2;
    }
}

// ---- k_gh: G = E@wa+ba (+ GT transposed store), H = E@wp+bp.
// 1024 one-wave blocks, 16x32 tiles. GT[j,i] from G's own accumulator ->
// bit-identical, so adjacency threshold g1+g2>0 is exact-consistent.
__global__ __launch_bounds__(64) void k_gh(
    const unsigned short* __restrict__ Epl,
    const unsigned short* __restrict__ WTa, const float* __restrict__ ba,
    const unsigned short* __restrict__ WTp, const float* __restrict__ bp,
    float* __restrict__ G, float* __restrict__ GT, float* __restrict__ H)
{
    int bid = blockIdx.x;
    int m = bid >> 9, b = (bid >> 7) & 3, t = bid & 127;
    int tm = t >> 3, tn = t & 7;
    const unsigned short* WT = m ? WTp : WTa;
    const float* bias = m ? bp : ba;
    float* C = (m ? H : G) + b * MAT;
    int l = threadIdx.x, l15 = l & 15, lk = (l >> 4) * 8, lk4 = l >> 4;

    f32x4 acc[2]; acc[0] = 0.0f; acc[1] = 0.0f;
    int arow = b * MAT + (tm * 16 + l15) * NN;
    int col0 = (tn * 32 + l15) * NN, col1 = (tn * 32 + 16 + l15) * NN;

    const int TP[6] = {0, 0, 1, 0, 1, 2}, TQ[6] = {0, 1, 0, 2, 1, 0};
#pragma unroll
    for (int k0 = 0; k0 < NN; k0 += 32) {
        int kb = k0 + lk;
        U8 aE[3], wv[3][2];
#pragma unroll
        for (int pp = 0; pp < 3; ++pp) {
            aE[pp].v = *(const bf16x8*)&Epl[pp * BMAT + arow + kb];
            wv[pp][0].v = *(const bf16x8*)&WT[pp * MAT + col0 + kb];
            wv[pp][1].v = *(const bf16x8*)&WT[pp * MAT + col1 + kb];
        }
#pragma unroll
        for (int t6 = 0; t6 < 6; ++t6)
#pragma unroll
            for (int cg = 0; cg < 2; ++cg)
                MFMA(acc[cg], aE[TP[t6]].v, wv[TQ[t6]][cg].v);
    }
#pragma unroll
    for (int cg = 0; cg < 2; ++cg) {
        int col = tn * 32 + cg * 16 + l15;
        float bv = bias[col];
#pragma unroll
        for (int r = 0; r < 4; ++r) {
            int row = tm * 16 + lk4 * 4 + r;
            C[row * NN + col] = acc[cg][r] + bv;
        }
        if (m == 0) {   // transposed store of (acc+bias) into GT, 16B/lane
            f32x4 tv;
#pragma unroll
            for (int r = 0; r < 4; ++r) tv[r] = acc[cg][r] + bv;
            *(f32x4*)&GT[b * MAT + col * NN + tm * 16 + lk4 * 4] = tv;
        }
    }
}

// ---- k_fsP: fused prep + D/N GEMM pair + divide/fallback + symmetrize.
// grid (136, NB) x 128: wave s handles (R=s?tj:ti rows) x (C=s?ti:tj cols).
// Per wave: read H R-rows (f32) -> lmax/rs/eL/eH in-register (exact max,
// deterministic order => bit-identical across blocks); read G/GT C-rows ->
// adjacency frags + cnt in-register. No eL/eH/adj global round-trip.
template<int FINAL>
__global__ __launch_bounds__(128) void k_fsP(
    const float* __restrict__ G, const float* __restrict__ GT,
    const float* __restrict__ H, const float* __restrict__ ae,
    unsigned short* __restrict__ Epl, float* __restrict__ out)
{
    __shared__ float Fs[2][16 * 17];
    __shared__ float rsL[2][16];
    int b = blockIdx.y;
    int ti = 0, rem = blockIdx.x;
    while (rem >= 16 - ti) { rem -= 16 - ti; ++ti; }
    int tj = ti + rem;
    int t = threadIdx.x, s = t >> 6, lane = t & 63, l15 = lane & 15, q = lane >> 4;
    int R = s ? tj : ti, C = s ? ti : tj;

    // S = sum(ae)
    float sv = 0.f;
#pragma unroll
    for (int k = 0; k < 8; ++k) sv += ae[lane + 64 * k];
    float S = wave_allsum(sv);

    // H rows for R-tile: lane (l15=row, q=chunk) holds cols it*32+q*8..+7
    float hrow[8][8];
    int hbase = b * MAT + (R * 16 + l15) * NN;
    float lmax = -3.4e38f, hsum = 0.f;
#pragma unroll
    for (int it = 0; it < 8; ++it) {
        f32x4 h0 = *(const f32x4*)&H[hbase + it * 32 + q * 8];
        f32x4 h1 = *(const f32x4*)&H[hbase + it * 32 + q * 8 + 4];
#pragma unroll
        for (int i = 0; i < 4; ++i) { hrow[it][i] = h0[i]; hrow[it][i + 4] = h1[i]; }
#pragma unroll
        for (int i = 0; i < 8; ++i) {
            float x = S * hrow[it][i];
            float L = (x > 0.f) ? x : ALPHA * x;
            lmax = fmaxf(lmax, L);
            hsum += hrow[it][i];
        }
    }
    lmax = fmaxf(lmax, __shfl_xor(lmax, 16, 64));
    lmax = fmaxf(lmax, __shfl_xor(lmax, 32, 64));   // exact row max
    hsum += __shfl_xor(hsum, 16, 64);
    hsum += __shfl_xor(hsum, 32, 64);
    if (q == 0) rsL[s][l15] = hsum;

    // adjacency frags + cnt for C-rows
    float cntp = 0.f;
    bf16x8 adjf[8];
    int gbase = b * MAT + (C * 16 + l15) * NN;
#pragma unroll
    for (int it = 0; it < 8; ++it) {
        f32x4 g0 = *(const f32x4*)&G[gbase + it * 32 + q * 8];
        f32x4 g1 = *(const f32x4*)&G[gbase + it * 32 + q * 8 + 4];
        f32x4 t0 = *(const f32x4*)&GT[gbase + it * 32 + q * 8];
        f32x4 t1 = *(const f32x4*)&GT[gbase + it * 32 + q * 8 + 4];
        U8 a_;
#pragma unroll
        for (int i = 0; i < 4; ++i) {
            bool b0 = (g0[i] + t0[i] > 0.f);
            bool b1 = (g1[i] + t1[i] > 0.f);
            cntp += (b0 ? 1.f : 0.f) + (b1 ? 1.f : 0.f);
            a_.u[i] = b0 ? 0x3F80 : 0;
            a_.u[i + 4] = b1 ? 0x3F80 : 0;
        }
        adjf[it] = a_.v;
    }
    cntp += __shfl_xor(cntp, 16, 64);
    cntp += __shfl_xor(cntp, 32, 64);   // lane l15: cnt[C*16+l15]

    // D/N MFMA with on-the-fly eL/eH 3-split fragments
    f32x4 aD = 0.f, aN = 0.f;
#pragma unroll
    for (int it = 0; it < 8; ++it) {
        U8 e0, e1, e2, q0, q1, q2;
#pragma unroll
        for (int i = 0; i < 8; ++i) {
            float x = S * hrow[it][i];
            float L = (x > 0.f) ? x : ALPHA * x;
            float e = __expf(L - lmax);
            float eh = e * hrow[it][i];
            split3(e,  e0.u[i], e1.u[i], e2.u[i]);
            split3(eh, q0.u[i], q1.u[i], q2.u[i]);
        }
        MFMA(aD, e0.v, adjf[it]); MFMA(aD, e1.v, adjf[it]); MFMA(aD, e2.v, adjf[it]);
        MFMA(aN, q0.v, adjf[it]); MFMA(aN, q1.v, adjf[it]); MFMA(aN, q2.v, adjf[it]);
    }

    // epilogue: divide/fallback, symmetrize via LDS exchange
    float F[4];
#pragma unroll
    for (int r = 0; r < 4; ++r) {
        int m = q * 4 + r;
        F[r] = (cntp > 0.5f) ? aN[r] / aD[r] : rsL[s][m] * (1.f / 256.f);
        Fs[s][m * 17 + l15] = F[r];
    }
    __syncthreads();
#pragma unroll
    for (int r = 0; r < 4; ++r) {
        int m = q * 4 + r;
        float e = 0.5f * (F[r] + Fs[1 ^ s][l15 * 17 + m]);
        int idx = b * MAT + (R * 16 + m) * NN + C * 16 + l15;
        if (FINAL) {
            float tv = tanhf(e);
            out[idx] = tv; out[BMAT + idx] = tv;
        } else {
            unsigned short s0, s1, s2;
            split3(e, s0, s1, s2);
            Epl[idx] = s0; Epl[BMAT + idx] = s1; Epl[2 * BMAT + idx] = s2;
        }
    }
}

extern "C" void kernel_launch(void* const* d_in, const int* in_sizes, int n_in,
                              void* d_out, int out_size, void* d_ws, size_t ws_size,
                              hipStream_t stream) {
    const float* edges = (const float*)d_in[1];
    const float* wp[2] = {(const float*)d_in[7],  (const float*)d_in[17]};
    const float* bp[2] = {(const float*)d_in[8],  (const float*)d_in[18]};
    const float* ae[2] = {(const float*)d_in[9],  (const float*)d_in[19]};
    const float* wa[2] = {(const float*)d_in[10], (const float*)d_in[20]};
    const float* ba[2] = {(const float*)d_in[11], (const float*)d_in[21]};
    float* out = (float*)d_out;

    // ws layout (~7.5 MB)
    unsigned short* WT   = (unsigned short*)d_ws;   // 12 planes * 128KB
    unsigned short* EplA = WT + 12 * MAT;           // 3 planes
    unsigned short* EplB = EplA + 3 * BMAT;         // 3 planes
    float* G  = (float*)(EplB + 3 * BMAT);          // 1MB
    float* GT = G + BMAT;                           // 1MB
    float* H  = GT + BMAT;                          // 1MB

    k_pre<<<1280, 256, 0, stream>>>(wa[0], wp[0], wa[1], wp[1], edges, WT, EplA);

    for (int l = 0; l < 2; ++l) {
        const unsigned short* WTa = WT + (l * 2 + 0) * 3 * MAT;
        const unsigned short* WTp = WT + (l * 2 + 1) * 3 * MAT;
        const unsigned short* Ein = l ? EplB : EplA;
        k_gh<<<1024, 64, 0, stream>>>(Ein, WTa, ba[l], WTp, bp[l], G, GT, H);
        if (l == 0)
            k_fsP<0><<<dim3(136, NB), 128, 0, stream>>>(G, GT, H, ae[l], EplB, nullptr);
        else
            k_fsP<1><<<dim3(136, NB), 128, 0, stream>>>(G, GT, H, ae[l], nullptr, out);
    }
}

// Round 11
// 63.955 us; speedup vs baseline: 2.1451x; 1.0484x over previous
//
#include <hip/hip_runtime.h>
#include <math.h>

#define NB 4
#define NN 256
#define MAT (NN*NN)      // 65536
#define BMAT (NB*MAT)    // 262144
#define ALPHA 0.2f

typedef __attribute__((ext_vector_type(8))) __bf16 bf16x8;
typedef __attribute__((ext_vector_type(4))) float f32x4;

union U8 { bf16x8 v; unsigned short u[8]; };

#define MFMA(acc, A, B) acc = __builtin_amdgcn_mfma_f32_16x16x32_bf16(A, B, acc, 0, 0, 0)

__device__ __forceinline__ unsigned short f2bf(float x) {
    unsigned u = __float_as_uint(x);
    u = (u + 0x7FFFu + ((u >> 16) & 1u)) >> 16;
    return (unsigned short)u;
}
__device__ __forceinline__ float bf2f(unsigned short h) {
    return __uint_as_float(((unsigned)h) << 16);
}
__device__ __forceinline__ void split3(float x, unsigned short& a,
                                       unsigned short& b, unsigned short& c) {
    a = f2bf(x); float r = x - bf2f(a);
    b = f2bf(r); r -= bf2f(b);
    c = f2bf(r);
}

__device__ __forceinline__ float wave_allsum(float v) {
#pragma unroll
    for (int o = 1; o < 64; o <<= 1) v += __shfl_xor(v, o, 64);
    return v;
}

// ---- k_gh: G = E@wa+ba (+ GT transposed store), H = E@wp+bp.
// 1024 one-wave blocks, 16x32 tiles. On-the-fly 3-split of W (f32, both
// layers) and of E (f32, layer 0 only; layer 1 reads the planes fsP wrote).
// split3 is pointwise => recomputed splits are bit-identical across blocks,
// so G/GT (same accumulator) and adjacency stay exact-consistent.
template<int L0>
__global__ __launch_bounds__(64) void k_gh(
    const float* __restrict__ Ef,            // layer0 input (f32)
    const unsigned short* __restrict__ Epl,  // layer1 input planes
    const float* __restrict__ Wa, const float* __restrict__ ba,
    const float* __restrict__ Wp, const float* __restrict__ bp,
    float* __restrict__ G, float* __restrict__ GT, float* __restrict__ H)
{
    int bid = blockIdx.x;
    int m = bid >> 9, b = (bid >> 7) & 3, t = bid & 127;
    int tm = t >> 3, tn = t & 7;
    const float* W = m ? Wp : Wa;
    const float* bias = m ? bp : ba;
    float* C = (m ? H : G) + b * MAT;
    int l = threadIdx.x, l15 = l & 15, lk = (l >> 4) * 8, lk4 = l >> 4;

    f32x4 acc[2]; acc[0] = 0.0f; acc[1] = 0.0f;
    int arow = b * MAT + (tm * 16 + l15) * NN;
    int col0 = tn * 32 + l15, col1 = tn * 32 + 16 + l15;

    const int TP[6] = {0, 0, 1, 0, 1, 2}, TQ[6] = {0, 1, 0, 2, 1, 0};
#pragma unroll
    for (int k0 = 0; k0 < NN; k0 += 32) {
        int kb = k0 + lk;
        U8 aE[3], wv[3][2];
        if (L0) {
            f32x4 e0 = *(const f32x4*)&Ef[arow + kb];
            f32x4 e1 = *(const f32x4*)&Ef[arow + kb + 4];
#pragma unroll
            for (int i = 0; i < 4; ++i) {
                split3(e0[i], aE[0].u[i], aE[1].u[i], aE[2].u[i]);
                split3(e1[i], aE[0].u[i + 4], aE[1].u[i + 4], aE[2].u[i + 4]);
            }
        } else {
#pragma unroll
            for (int pp = 0; pp < 3; ++pp)
                aE[pp].v = *(const bf16x8*)&Epl[pp * BMAT + arow + kb];
        }
#pragma unroll
        for (int cg = 0; cg < 2; ++cg) {
            int colc = cg ? col1 : col0;
#pragma unroll
            for (int kk = 0; kk < 8; ++kk) {
                float wf = W[(kb + kk) * NN + colc];
                split3(wf, wv[0][cg].u[kk], wv[1][cg].u[kk], wv[2][cg].u[kk]);
            }
        }
#pragma unroll
        for (int t6 = 0; t6 < 6; ++t6)
#pragma unroll
            for (int cg = 0; cg < 2; ++cg)
                MFMA(acc[cg], aE[TP[t6]].v, wv[TQ[t6]][cg].v);
    }
#pragma unroll
    for (int cg = 0; cg < 2; ++cg) {
        int col = tn * 32 + cg * 16 + l15;
        float bv = bias[col];
#pragma unroll
        for (int r = 0; r < 4; ++r) {
            int row = tm * 16 + lk4 * 4 + r;
            C[row * NN + col] = acc[cg][r] + bv;
        }
        if (m == 0) {   // transposed store of (acc+bias) into GT, 16B/lane
            f32x4 tv;
#pragma unroll
            for (int r = 0; r < 4; ++r) tv[r] = acc[cg][r] + bv;
            *(f32x4*)&GT[b * MAT + col * NN + tm * 16 + lk4 * 4] = tv;
        }
    }
}

// ---- k_fsP: fused prep + D/N GEMM pair + divide/fallback + symmetrize.
// grid (136, NB) x 128: wave s handles (R=s?tj:ti rows) x (C=s?ti:tj cols).
template<int FINAL>
__global__ __launch_bounds__(128) void k_fsP(
    const float* __restrict__ G, const float* __restrict__ GT,
    const float* __restrict__ H, const float* __restrict__ ae,
    unsigned short* __restrict__ Epl, float* __restrict__ out)
{
    __shared__ float Fs[2][16 * 17];
    __shared__ float rsL[2][16];
    int b = blockIdx.y;
    int ti = 0, rem = blockIdx.x;
    while (rem >= 16 - ti) { rem -= 16 - ti; ++ti; }
    int tj = ti + rem;
    int t = threadIdx.x, s = t >> 6, lane = t & 63, l15 = lane & 15, q = lane >> 4;
    int R = s ? tj : ti, C = s ? ti : tj;

    // S = sum(ae)
    float sv = 0.f;
#pragma unroll
    for (int k = 0; k < 8; ++k) sv += ae[lane + 64 * k];
    float S = wave_allsum(sv);

    // H rows for R-tile: lane (l15=row, q=chunk) holds cols it*32+q*8..+7
    float hrow[8][8];
    int hbase = b * MAT + (R * 16 + l15) * NN;
    float lmax = -3.4e38f, hsum = 0.f;
#pragma unroll
    for (int it = 0; it < 8; ++it) {
        f32x4 h0 = *(const f32x4*)&H[hbase + it * 32 + q * 8];
        f32x4 h1 = *(const f32x4*)&H[hbase + it * 32 + q * 8 + 4];
#pragma unroll
        for (int i = 0; i < 4; ++i) { hrow[it][i] = h0[i]; hrow[it][i + 4] = h1[i]; }
#pragma unroll
        for (int i = 0; i < 8; ++i) {
            float x = S * hrow[it][i];
            float L = (x > 0.f) ? x : ALPHA * x;
            lmax = fmaxf(lmax, L);
            hsum += hrow[it][i];
        }
    }
    lmax = fmaxf(lmax, __shfl_xor(lmax, 16, 64));
    lmax = fmaxf(lmax, __shfl_xor(lmax, 32, 64));   // exact row max
    hsum += __shfl_xor(hsum, 16, 64);
    hsum += __shfl_xor(hsum, 32, 64);
    if (q == 0) rsL[s][l15] = hsum;

    // adjacency frags + cnt for C-rows
    float cntp = 0.f;
    bf16x8 adjf[8];
    int gbase = b * MAT + (C * 16 + l15) * NN;
#pragma unroll
    for (int it = 0; it < 8; ++it) {
        f32x4 g0 = *(const f32x4*)&G[gbase + it * 32 + q * 8];
        f32x4 g1 = *(const f32x4*)&G[gbase + it * 32 + q * 8 + 4];
        f32x4 t0 = *(const f32x4*)&GT[gbase + it * 32 + q * 8];
        f32x4 t1 = *(const f32x4*)&GT[gbase + it * 32 + q * 8 + 4];
        U8 a_;
#pragma unroll
        for (int i = 0; i < 4; ++i) {
            bool b0 = (g0[i] + t0[i] > 0.f);
            bool b1 = (g1[i] + t1[i] > 0.f);
            cntp += (b0 ? 1.f : 0.f) + (b1 ? 1.f : 0.f);
            a_.u[i] = b0 ? 0x3F80 : 0;
            a_.u[i + 4] = b1 ? 0x3F80 : 0;
        }
        adjf[it] = a_.v;
    }
    cntp += __shfl_xor(cntp, 16, 64);
    cntp += __shfl_xor(cntp, 32, 64);   // lane l15: cnt[C*16+l15]

    // D/N MFMA with on-the-fly eL/eH 3-split fragments
    f32x4 aD = 0.f, aN = 0.f;
#pragma unroll
    for (int it = 0; it < 8; ++it) {
        U8 e0, e1, e2, q0, q1, q2;
#pragma unroll
        for (int i = 0; i < 8; ++i) {
            float x = S * hrow[it][i];
            float L = (x > 0.f) ? x : ALPHA * x;
            float e = __expf(L - lmax);
            float eh = e * hrow[it][i];
            split3(e,  e0.u[i], e1.u[i], e2.u[i]);
            split3(eh, q0.u[i], q1.u[i], q2.u[i]);
        }
        MFMA(aD, e0.v, adjf[it]); MFMA(aD, e1.v, adjf[it]); MFMA(aD, e2.v, adjf[it]);
        MFMA(aN, q0.v, adjf[it]); MFMA(aN, q1.v, adjf[it]); MFMA(aN, q2.v, adjf[it]);
    }

    // epilogue: divide/fallback, symmetrize via LDS exchange
    float F[4];
#pragma unroll
    for (int r = 0; r < 4; ++r) {
        int m = q * 4 + r;
        F[r] = (cntp > 0.5f) ? aN[r] / aD[r] : rsL[s][m] * (1.f / 256.f);
        Fs[s][m * 17 + l15] = F[r];
    }
    __syncthreads();
#pragma unroll
    for (int r = 0; r < 4; ++r) {
        int m = q * 4 + r;
        float e = 0.5f * (F[r] + Fs[1 ^ s][l15 * 17 + m]);
        int idx = b * MAT + (R * 16 + m) * NN + C * 16 + l15;
        if (FINAL) {
            float tv = tanhf(e);
            out[idx] = tv; out[BMAT + idx] = tv;
        } else {
            unsigned short s0, s1, s2;
            split3(e, s0, s1, s2);
            Epl[idx] = s0; Epl[BMAT + idx] = s1; Epl[2 * BMAT + idx] = s2;
        }
    }
}

extern "C" void kernel_launch(void* const* d_in, const int* in_sizes, int n_in,
                              void* d_out, int out_size, void* d_ws, size_t ws_size,
                              hipStream_t stream) {
    const float* edges = (const float*)d_in[1];
    const float* wp[2] = {(const float*)d_in[7],  (const float*)d_in[17]};
    const float* bp[2] = {(const float*)d_in[8],  (const float*)d_in[18]};
    const float* ae[2] = {(const float*)d_in[9],  (const float*)d_in[19]};
    const float* wa[2] = {(const float*)d_in[10], (const float*)d_in[20]};
    const float* ba[2] = {(const float*)d_in[11], (const float*)d_in[21]};
    float* out = (float*)d_out;

    // ws layout (~4.5 MB)
    unsigned short* EplB = (unsigned short*)d_ws;    // 3 planes (layer-1 input)
    float* G  = (float*)(EplB + 3 * BMAT);           // 1MB
    float* GT = G + BMAT;                            // 1MB
    float* H  = GT + BMAT;                           // 1MB

    // layer 0: E from f32 edges (on-the-fly split), W f32 on-the-fly
    k_gh<1><<<1024, 64, 0, stream>>>(edges, nullptr, wa[0], ba[0], wp[0], bp[0],
                                     G, GT, H);
    k_fsP<0><<<dim3(136, NB), 128, 0, stream>>>(G, GT, H, ae[0], EplB, nullptr);
    // layer 1: E from EplB planes, W f32 on-the-fly
    k_gh<0><<<1024, 64, 0, stream>>>(nullptr, EplB, wa[1], ba[1], wp[1], bp[1],
                                     G, GT, H);
    k_fsP<1><<<dim3(136, NB), 128, 0, stream>>>(G, GT, H, ae[1], nullptr, out);
}

// Round 12
// 58.601 us; speedup vs baseline: 2.3411x; 1.0914x over previous
//
#include <hip/hip_runtime.h>
#include <math.h>

#define NB 4
#define NN 256
#define MAT (NN*NN)      // 65536
#define BMAT (NB*MAT)    // 262144
#define ALPHA 0.2f

typedef __attribute__((ext_vector_type(8))) __bf16 bf16x8;
typedef __attribute__((ext_vector_type(4))) float f32x4;

union U8 { bf16x8 v; unsigned short u[8]; };

#define MFMA(acc, A, B) acc = __builtin_amdgcn_mfma_f32_16x16x32_bf16(A, B, acc, 0, 0, 0)

__device__ __forceinline__ unsigned short f2bf(float x) {
    unsigned u = __float_as_uint(x);
    u = (u + 0x7FFFu + ((u >> 16) & 1u)) >> 16;
    return (unsigned short)u;
}
__device__ __forceinline__ float bf2f(unsigned short h) {
    return __uint_as_float(((unsigned)h) << 16);
}
__device__ __forceinline__ void split3(float x, unsigned short& a,
                                       unsigned short& b, unsigned short& c) {
    a = f2bf(x); float r = x - bf2f(a);
    b = f2bf(r); r -= bf2f(b);
    c = f2bf(r);
}

__device__ __forceinline__ float wave_sum(float v) {
#pragma unroll
    for (int o = 32; o > 0; o >>= 1) v += __shfl_down(v, o, 64);
    return v;
}
__device__ __forceinline__ float block_sum256(float v, volatile float* red) {
    int lane = threadIdx.x & 63, w = threadIdx.x >> 6;
    v = wave_sum(v);
    __syncthreads();
    if (lane == 0) red[w] = v;
    __syncthreads();
    return red[0] + red[1] + red[2] + red[3];
}

// ---- k_gh: G = E@wa+ba (+ GT transposed store), H = E@wp+bp.
// 2048 one-wave blocks, 16x16 tiles (2 waves/SIMD for latency hiding).
// MFMA chain order identical to r11 -> G/GT/H bit-identical -> adjacency safe.
template<int L0>
__global__ __launch_bounds__(64) void k_gh(
    const float* __restrict__ Ef,            // layer0 input (f32)
    const unsigned short* __restrict__ Epl,  // layer1 input planes
    const float* __restrict__ Wa, const float* __restrict__ ba,
    const float* __restrict__ Wp, const float* __restrict__ bp,
    float* __restrict__ G, float* __restrict__ GT, float* __restrict__ H)
{
    int bid = blockIdx.x;
    int m = bid >> 10, b = (bid >> 8) & 3, t = bid & 255;
    int tm = t >> 4, tn = t & 15;
    const float* W = m ? Wp : Wa;
    const float* bias = m ? bp : ba;
    float* C = (m ? H : G) + b * MAT;
    int l = threadIdx.x, l15 = l & 15, lk = (l >> 4) * 8, lk4 = l >> 4;

    f32x4 acc = 0.0f;
    int arow = b * MAT + (tm * 16 + l15) * NN;
    int col = tn * 16 + l15;

    const int TP[6] = {0, 0, 1, 0, 1, 2}, TQ[6] = {0, 1, 0, 2, 1, 0};
#pragma unroll
    for (int k0 = 0; k0 < NN; k0 += 32) {
        int kb = k0 + lk;
        U8 aE[3], wv[3];
        if (L0) {
            f32x4 e0 = *(const f32x4*)&Ef[arow + kb];
            f32x4 e1 = *(const f32x4*)&Ef[arow + kb + 4];
#pragma unroll
            for (int i = 0; i < 4; ++i) {
                split3(e0[i], aE[0].u[i], aE[1].u[i], aE[2].u[i]);
                split3(e1[i], aE[0].u[i + 4], aE[1].u[i + 4], aE[2].u[i + 4]);
            }
        } else {
#pragma unroll
            for (int pp = 0; pp < 3; ++pp)
                aE[pp].v = *(const bf16x8*)&Epl[pp * BMAT + arow + kb];
        }
#pragma unroll
        for (int kk = 0; kk < 8; ++kk) {
            float wf = W[(kb + kk) * NN + col];
            split3(wf, wv[0].u[kk], wv[1].u[kk], wv[2].u[kk]);
        }
#pragma unroll
        for (int t6 = 0; t6 < 6; ++t6)
            MFMA(acc, aE[TP[t6]].v, wv[TQ[t6]].v);
    }
    float bv = bias[col];
#pragma unroll
    for (int r = 0; r < 4; ++r) {
        int row = tm * 16 + lk4 * 4 + r;
        C[row * NN + col] = acc[r] + bv;
    }
    if (m == 0) {   // transposed store of (acc+bias) into GT, 16B/lane
        f32x4 tv;
#pragma unroll
        for (int r = 0; r < 4; ++r) tv[r] = acc[r] + bv;
        *(f32x4*)&GT[b * MAT + col * NN + tm * 16 + lk4 * 4] = tv;
    }
}

// ---- k_fsP: fused prep + D/N GEMM pair + divide/fallback + symmetrize.
// grid (136, NB) x 256: wave w -> side=w>>1 (A: rows ti/cols tj; B: swapped),
// half=w&1 (K-cols [half*128, half*128+128)). Partial stats/accums combined
// via LDS. lmax exact (order-free); cnt exact (0/1 sums); D/N reorder smooth.
template<int FINAL>
__global__ __launch_bounds__(256) void k_fsP(
    const float* __restrict__ G, const float* __restrict__ GT,
    const float* __restrict__ H, const float* __restrict__ ae,
    unsigned short* __restrict__ Epl, float* __restrict__ out)
{
    __shared__ float Fs[2][16 * 17];
    __shared__ float lst[2][2][16], hst[2][2][16], cst[2][2][16];
    __shared__ f32x4 pD[4][64], pN[4][64];
    __shared__ float red[4];
    int b = blockIdx.y;
    int ti = 0, rem = blockIdx.x;
    while (rem >= 16 - ti) { rem -= 16 - ti; ++ti; }
    int tj = ti + rem;
    int t = threadIdx.x, w = t >> 6, lane = t & 63, l15 = lane & 15, q = lane >> 4;
    int side = w >> 1, half = w & 1;
    int R = side ? tj : ti, C = side ? ti : tj;

    // S = sum(ae) (block-wide, deterministic)
    float S = block_sum256(ae[t] + ae[t + 256], red);

    // H prep: this wave's half of R-tile rows (cols half*128 + it*32 + q*8)
    float hrow[4][8];
    int hbase = b * MAT + (R * 16 + l15) * NN + half * 128;
    float lmax = -3.4e38f, hsum = 0.f;
#pragma unroll
    for (int it = 0; it < 4; ++it) {
        f32x4 h0 = *(const f32x4*)&H[hbase + it * 32 + q * 8];
        f32x4 h1 = *(const f32x4*)&H[hbase + it * 32 + q * 8 + 4];
#pragma unroll
        for (int i = 0; i < 4; ++i) { hrow[it][i] = h0[i]; hrow[it][i + 4] = h1[i]; }
#pragma unroll
        for (int i = 0; i < 8; ++i) {
            float x = S * hrow[it][i];
            float L = (x > 0.f) ? x : ALPHA * x;
            lmax = fmaxf(lmax, L);
            hsum += hrow[it][i];
        }
    }
    lmax = fmaxf(lmax, __shfl_xor(lmax, 16, 64));
    lmax = fmaxf(lmax, __shfl_xor(lmax, 32, 64));
    hsum += __shfl_xor(hsum, 16, 64);
    hsum += __shfl_xor(hsum, 32, 64);
    if (q == 0) { lst[side][half][l15] = lmax; hst[side][half][l15] = hsum; }

    // adjacency frags + cnt partial for this wave's half of C-rows
    float cntp = 0.f;
    bf16x8 adjf[4];
    int gbase = b * MAT + (C * 16 + l15) * NN + half * 128;
#pragma unroll
    for (int it = 0; it < 4; ++it) {
        f32x4 g0 = *(const f32x4*)&G[gbase + it * 32 + q * 8];
        f32x4 g1 = *(const f32x4*)&G[gbase + it * 32 + q * 8 + 4];
        f32x4 t0 = *(const f32x4*)&GT[gbase + it * 32 + q * 8];
        f32x4 t1 = *(const f32x4*)&GT[gbase + it * 32 + q * 8 + 4];
        U8 a_;
#pragma unroll
        for (int i = 0; i < 4; ++i) {
            bool b0 = (g0[i] + t0[i] > 0.f);
            bool b1 = (g1[i] + t1[i] > 0.f);
            cntp += (b0 ? 1.f : 0.f) + (b1 ? 1.f : 0.f);
            a_.u[i] = b0 ? 0x3F80 : 0;
            a_.u[i + 4] = b1 ? 0x3F80 : 0;
        }
        adjf[it] = a_.v;
    }
    cntp += __shfl_xor(cntp, 16, 64);
    cntp += __shfl_xor(cntp, 32, 64);
    if (q == 0) cst[side][half][l15] = cntp;
    __syncthreads();

    // combined exact row max for this side
    float lmaxC = fmaxf(lst[side][0][l15], lst[side][1][l15]);

    // D/N MFMA with on-the-fly eL/eH 3-split fragments (half-K partials)
    f32x4 aD = 0.f, aN = 0.f;
#pragma unroll
    for (int it = 0; it < 4; ++it) {
        U8 e0, e1, e2, q0, q1, q2;
#pragma unroll
        for (int i = 0; i < 8; ++i) {
            float x = S * hrow[it][i];
            float L = (x > 0.f) ? x : ALPHA * x;
            float e = __expf(L - lmaxC);
            float eh = e * hrow[it][i];
            split3(e,  e0.u[i], e1.u[i], e2.u[i]);
            split3(eh, q0.u[i], q1.u[i], q2.u[i]);
        }
        MFMA(aD, e0.v, adjf[it]); MFMA(aD, e1.v, adjf[it]); MFMA(aD, e2.v, adjf[it]);
        MFMA(aN, q0.v, adjf[it]); MFMA(aN, q1.v, adjf[it]); MFMA(aN, q2.v, adjf[it]);
    }
    pD[w][lane] = aD;
    pN[w][lane] = aN;
    __syncthreads();

    // epilogue on waves 0 (side A) and 2 (side B)
    float F[4] = {0.f, 0.f, 0.f, 0.f};
    if (half == 0) {
        float cntC = cst[side][0][l15] + cst[side][1][l15];
#pragma unroll
        for (int r = 0; r < 4; ++r) {
            int m = q * 4 + r;
            float dv = pD[2 * side][lane][r] + pD[2 * side + 1][lane][r];
            float nv = pN[2 * side][lane][r] + pN[2 * side + 1][lane][r];
            float rsv = (hst[side][0][m] + hst[side][1][m]) * (1.f / 256.f);
            F[r] = (cntC > 0.5f) ? nv / dv : rsv;
            Fs[side][m * 17 + l15] = F[r];
        }
    }
    __syncthreads();
    if (half == 0) {
#pragma unroll
        for (int r = 0; r < 4; ++r) {
            int m = q * 4 + r;
            float e = 0.5f * (F[r] + Fs[1 ^ side][l15 * 17 + m]);
            int idx = b * MAT + (R * 16 + m) * NN + C * 16 + l15;
            if (FINAL) {
                float tv = tanhf(e);
                out[idx] = tv; out[BMAT + idx] = tv;
            } else {
                unsigned short s0, s1, s2;
                split3(e, s0, s1, s2);
                Epl[idx] = s0; Epl[BMAT + idx] = s1; Epl[2 * BMAT + idx] = s2;
            }
        }
    }
}

extern "C" void kernel_launch(void* const* d_in, const int* in_sizes, int n_in,
                              void* d_out, int out_size, void* d_ws, size_t ws_size,
                              hipStream_t stream) {
    const float* edges = (const float*)d_in[1];
    const float* wp[2] = {(const float*)d_in[7],  (const float*)d_in[17]};
    const float* bp[2] = {(const float*)d_in[8],  (const float*)d_in[18]};
    const float* ae[2] = {(const float*)d_in[9],  (const float*)d_in[19]};
    const float* wa[2] = {(const float*)d_in[10], (const float*)d_in[20]};
    const float* ba[2] = {(const float*)d_in[11], (const float*)d_in[21]};
    float* out = (float*)d_out;

    // ws layout (~4.5 MB)
    unsigned short* EplB = (unsigned short*)d_ws;    // 3 planes (layer-1 input)
    float* G  = (float*)(EplB + 3 * BMAT);           // 1MB
    float* GT = G + BMAT;                            // 1MB
    float* H  = GT + BMAT;                           // 1MB

    k_gh<1><<<2048, 64, 0, stream>>>(edges, nullptr, wa[0], ba[0], wp[0], bp[0],
                                     G, GT, H);
    k_fsP<0><<<dim3(136, NB), 256, 0, stream>>>(G, GT, H, ae[0], EplB, nullptr);
    k_gh<0><<<2048, 64, 0, stream>>>(nullptr, EplB, wa[1], ba[1], wp[1], bp[1],
                                     G, GT, H);
    k_fsP<1><<<dim3(136, NB), 256, 0, stream>>>(G, GT, H, ae[1], nullptr, out);
}

// Round 13
// 58.553 us; speedup vs baseline: 2.3430x; 1.0008x over previous
//
#include <hip/hip_runtime.h>
#include <math.h>

#define NB 4
#define NN 256
#define MAT (NN*NN)      // 65536
#define BMAT (NB*MAT)    // 262144
#define ALPHA 0.2f

typedef __attribute__((ext_vector_type(8))) __bf16 bf16x8;
typedef __attribute__((ext_vector_type(4))) float f32x4;

union U8 { bf16x8 v; unsigned short u[8]; };

#define MFMA(acc, A, B) acc = __builtin_amdgcn_mfma_f32_16x16x32_bf16(A, B, acc, 0, 0, 0)

__device__ __forceinline__ unsigned short f2bf(float x) {
    unsigned u = __float_as_uint(x);
    u = (u + 0x7FFFu + ((u >> 16) & 1u)) >> 16;
    return (unsigned short)u;
}
__device__ __forceinline__ float bf2f(unsigned short h) {
    return __uint_as_float(((unsigned)h) << 16);
}
__device__ __forceinline__ void split3(float x, unsigned short& a,
                                       unsigned short& b, unsigned short& c) {
    a = f2bf(x); float r = x - bf2f(a);
    b = f2bf(r); r -= bf2f(b);
    c = f2bf(r);
}

__device__ __forceinline__ float wave_allsum(float v) {
#pragma unroll
    for (int o = 1; o < 64; o <<= 1) v += __shfl_xor(v, o, 64);
    return v;
}

// ---- k_gh: G = E@wa+ba (+ GT transposed store), H = E@wp+bp.
// 2048 blocks x 128 thr: one 16x16 tile per block, wave h owns K-half.
// Partials combined low+high (deterministic, same for G and GT -> adjacency
// self-consistent). 4096 waves = 4/SIMD.
template<int L0>
__global__ __launch_bounds__(128) void k_gh(
    const float* __restrict__ Ef,            // layer0 input (f32)
    const unsigned short* __restrict__ Epl,  // layer1 input planes
    const float* __restrict__ Wa, const float* __restrict__ ba,
    const float* __restrict__ Wp, const float* __restrict__ bp,
    float* __restrict__ G, float* __restrict__ GT, float* __restrict__ H)
{
    __shared__ f32x4 part[64];
    int bid = blockIdx.x;
    int m = bid >> 10, b = (bid >> 8) & 3, t = bid & 255;
    int tm = t >> 4, tn = t & 15;
    const float* W = m ? Wp : Wa;
    const float* bias = m ? bp : ba;
    float* C = (m ? H : G) + b * MAT;
    int tid = threadIdx.x, h = tid >> 6, lane = tid & 63;
    int l15 = lane & 15, lk = (lane >> 4) * 8, lk4 = lane >> 4;

    f32x4 acc = 0.0f;
    int arow = b * MAT + (tm * 16 + l15) * NN;
    int col = tn * 16 + l15;

    const int TP[6] = {0, 0, 1, 0, 1, 2}, TQ[6] = {0, 1, 0, 2, 1, 0};
#pragma unroll
    for (int ks = 0; ks < 4; ++ks) {
        int kb = h * 128 + ks * 32 + lk;
        U8 aE[3], wv[3];
        if (L0) {
            f32x4 e0 = *(const f32x4*)&Ef[arow + kb];
            f32x4 e1 = *(const f32x4*)&Ef[arow + kb + 4];
#pragma unroll
            for (int i = 0; i < 4; ++i) {
                split3(e0[i], aE[0].u[i], aE[1].u[i], aE[2].u[i]);
                split3(e1[i], aE[0].u[i + 4], aE[1].u[i + 4], aE[2].u[i + 4]);
            }
        } else {
#pragma unroll
            for (int pp = 0; pp < 3; ++pp)
                aE[pp].v = *(const bf16x8*)&Epl[pp * BMAT + arow + kb];
        }
#pragma unroll
        for (int kk = 0; kk < 8; ++kk) {
            float wf = W[(kb + kk) * NN + col];
            split3(wf, wv[0].u[kk], wv[1].u[kk], wv[2].u[kk]);
        }
#pragma unroll
        for (int t6 = 0; t6 < 6; ++t6)
            MFMA(acc, aE[TP[t6]].v, wv[TQ[t6]].v);
    }
    if (h == 1) part[lane] = acc;
    __syncthreads();
    if (h == 0) {
        f32x4 hi = part[lane];
        float bv = bias[col];
        f32x4 tv;
#pragma unroll
        for (int r = 0; r < 4; ++r) tv[r] = (acc[r] + hi[r]) + bv;
#pragma unroll
        for (int r = 0; r < 4; ++r)
            C[(tm * 16 + lk4 * 4 + r) * NN + col] = tv[r];
        if (m == 0)
            *(f32x4*)&GT[b * MAT + col * NN + tm * 16 + lk4 * 4] = tv;
    }
}

// ---- k_fsP: fused prep + D/N GEMM pair + divide/fallback + symmetrize.
// grid (136, NB) x 512: wave w -> side=w>>2, quarter=w&3 (64 K-cols each).
// lmax/cnt combine exactly; D/N fixed-order 4-way partial sum (smooth).
template<int FINAL>
__global__ __launch_bounds__(512) void k_fsP(
    const float* __restrict__ G, const float* __restrict__ GT,
    const float* __restrict__ H, const float* __restrict__ ae,
    unsigned short* __restrict__ Epl, float* __restrict__ out)
{
    __shared__ float Fs[2][16 * 17];
    __shared__ float lst[2][4][16], hst[2][4][16], cst[2][4][16];
    __shared__ f32x4 pD[8][64], pN[8][64];
    int b = blockIdx.y;
    int ti = 0, rem = blockIdx.x;
    while (rem >= 16 - ti) { rem -= 16 - ti; ++ti; }
    int tj = ti + rem;
    int t = threadIdx.x, w = t >> 6, lane = t & 63, l15 = lane & 15, q = lane >> 4;
    int side = w >> 2, quar = w & 3;
    int R = side ? tj : ti, C = side ? ti : tj;

    // S = sum(ae): per-wave, identical deterministic order in every wave
    float sv = 0.f;
#pragma unroll
    for (int k = 0; k < 8; ++k) sv += ae[lane + 64 * k];
    float S = wave_allsum(sv);

    // H prep: R-tile rows, this wave's K-quarter (cols quar*64 + it*32 + q*8)
    float hrow[2][8];
    int hbase = b * MAT + (R * 16 + l15) * NN + quar * 64;
    float lmax = -3.4e38f, hsum = 0.f;
#pragma unroll
    for (int it = 0; it < 2; ++it) {
        f32x4 h0 = *(const f32x4*)&H[hbase + it * 32 + q * 8];
        f32x4 h1 = *(const f32x4*)&H[hbase + it * 32 + q * 8 + 4];
#pragma unroll
        for (int i = 0; i < 4; ++i) { hrow[it][i] = h0[i]; hrow[it][i + 4] = h1[i]; }
#pragma unroll
        for (int i = 0; i < 8; ++i) {
            float x = S * hrow[it][i];
            float L = (x > 0.f) ? x : ALPHA * x;
            lmax = fmaxf(lmax, L);
            hsum += hrow[it][i];
        }
    }
    lmax = fmaxf(lmax, __shfl_xor(lmax, 16, 64));
    lmax = fmaxf(lmax, __shfl_xor(lmax, 32, 64));
    hsum += __shfl_xor(hsum, 16, 64);
    hsum += __shfl_xor(hsum, 32, 64);
    if (q == 0) { lst[side][quar][l15] = lmax; hst[side][quar][l15] = hsum; }

    // adjacency frags + cnt partial for C-rows, this wave's K-quarter
    float cntp = 0.f;
    bf16x8 adjf[2];
    int gbase = b * MAT + (C * 16 + l15) * NN + quar * 64;
#pragma unroll
    for (int it = 0; it < 2; ++it) {
        f32x4 g0 = *(const f32x4*)&G[gbase + it * 32 + q * 8];
        f32x4 g1 = *(const f32x4*)&G[gbase + it * 32 + q * 8 + 4];
        f32x4 t0 = *(const f32x4*)&GT[gbase + it * 32 + q * 8];
        f32x4 t1 = *(const f32x4*)&GT[gbase + it * 32 + q * 8 + 4];
        U8 a_;
#pragma unroll
        for (int i = 0; i < 4; ++i) {
            bool b0 = (g0[i] + t0[i] > 0.f);
            bool b1 = (g1[i] + t1[i] > 0.f);
            cntp += (b0 ? 1.f : 0.f) + (b1 ? 1.f : 0.f);
            a_.u[i] = b0 ? 0x3F80 : 0;
            a_.u[i + 4] = b1 ? 0x3F80 : 0;
        }
        adjf[it] = a_.v;
    }
    cntp += __shfl_xor(cntp, 16, 64);
    cntp += __shfl_xor(cntp, 32, 64);
    if (q == 0) cst[side][quar][l15] = cntp;
    __syncthreads();

    // combined exact row max for this side
    float lmaxC = fmaxf(fmaxf(lst[side][0][l15], lst[side][1][l15]),
                        fmaxf(lst[side][2][l15], lst[side][3][l15]));

    // D/N MFMA with on-the-fly eL/eH 3-split fragments (quarter-K partials)
    f32x4 aD = 0.f, aN = 0.f;
#pragma unroll
    for (int it = 0; it < 2; ++it) {
        U8 e0, e1, e2, q0, q1, q2;
#pragma unroll
        for (int i = 0; i < 8; ++i) {
            float x = S * hrow[it][i];
            float L = (x > 0.f) ? x : ALPHA * x;
            float e = __expf(L - lmaxC);
            float eh = e * hrow[it][i];
            split3(e,  e0.u[i], e1.u[i], e2.u[i]);
            split3(eh, q0.u[i], q1.u[i], q2.u[i]);
        }
        MFMA(aD, e0.v, adjf[it]); MFMA(aD, e1.v, adjf[it]); MFMA(aD, e2.v, adjf[it]);
        MFMA(aN, q0.v, adjf[it]); MFMA(aN, q1.v, adjf[it]); MFMA(aN, q2.v, adjf[it]);
    }
    pD[w][lane] = aD;
    pN[w][lane] = aN;
    __syncthreads();

    // epilogue on quarter-0 waves (one per side)
    float F[4] = {0.f, 0.f, 0.f, 0.f};
    if (quar == 0) {
        float cntC = ((cst[side][0][l15] + cst[side][1][l15]) +
                      cst[side][2][l15]) + cst[side][3][l15];
#pragma unroll
        for (int r = 0; r < 4; ++r) {
            int m = q * 4 + r;
            float dv = ((pD[4*side][lane][r] + pD[4*side+1][lane][r]) +
                        pD[4*side+2][lane][r]) + pD[4*side+3][lane][r];
            float nv = ((pN[4*side][lane][r] + pN[4*side+1][lane][r]) +
                        pN[4*side+2][lane][r]) + pN[4*side+3][lane][r];
            float rsv = (((hst[side][0][m] + hst[side][1][m]) +
                          hst[side][2][m]) + hst[side][3][m]) * (1.f / 256.f);
            F[r] = (cntC > 0.5f) ? nv / dv : rsv;
            Fs[side][m * 17 + l15] = F[r];
        }
    }
    __syncthreads();
    if (quar == 0) {
#pragma unroll
        for (int r = 0; r < 4; ++r) {
            int m = q * 4 + r;
            float e = 0.5f * (F[r] + Fs[1 ^ side][l15 * 17 + m]);
            int idx = b * MAT + (R * 16 + m) * NN + C * 16 + l15;
            if (FINAL) {
                float tv = tanhf(e);
                out[idx] = tv; out[BMAT + idx] = tv;
            } else {
                unsigned short s0, s1, s2;
                split3(e, s0, s1, s2);
                Epl[idx] = s0; Epl[BMAT + idx] = s1; Epl[2 * BMAT + idx] = s2;
            }
        }
    }
}

extern "C" void kernel_launch(void* const* d_in, const int* in_sizes, int n_in,
                              void* d_out, int out_size, void* d_ws, size_t ws_size,
                              hipStream_t stream) {
    const float* edges = (const float*)d_in[1];
    const float* wp[2] = {(const float*)d_in[7],  (const float*)d_in[17]};
    const float* bp[2] = {(const float*)d_in[8],  (const float*)d_in[18]};
    const float* ae[2] = {(const float*)d_in[9],  (const float*)d_in[19]};
    const float* wa[2] = {(const float*)d_in[10], (const float*)d_in[20]};
    const float* ba[2] = {(const float*)d_in[11], (const float*)d_in[21]};
    float* out = (float*)d_out;

    // ws layout (~4.5 MB)
    unsigned short* EplB = (unsigned short*)d_ws;    // 3 planes (layer-1 input)
    float* G  = (float*)(EplB + 3 * BMAT);           // 1MB
    float* GT = G + BMAT;                            // 1MB
    float* H  = GT + BMAT;                           // 1MB

    k_gh<1><<<2048, 128, 0, stream>>>(edges, nullptr, wa[0], ba[0], wp[0], bp[0],
                                      G, GT, H);
    k_fsP<0><<<dim3(136, NB), 512, 0, stream>>>(G, GT, H, ae[0], EplB, nullptr);
    k_gh<0><<<2048, 128, 0, stream>>>(nullptr, EplB, wa[1], ba[1], wp[1], bp[1],
                                      G, GT, H);
    k_fsP<1><<<dim3(136, NB), 512, 0, stream>>>(G, GT, H, ae[1], nullptr, out);
}

// Round 14
// 53.617 us; speedup vs baseline: 2.5587x; 1.0921x over previous
//
#include <hip/hip_runtime.h>
#include <math.h>

#define NB 4
#define NN 256
#define MAT (NN*NN)      // 65536
#define BMAT (NB*MAT)    // 262144
#define ALPHA 0.2f

typedef __attribute__((ext_vector_type(8))) __bf16 bf16x8;
typedef __attribute__((ext_vector_type(4))) float f32x4;

union U8 { bf16x8 v; unsigned short u[8]; };

#define MFMA(acc, A, B) acc = __builtin_amdgcn_mfma_f32_16x16x32_bf16(A, B, acc, 0, 0, 0)

__device__ __forceinline__ unsigned short f2bf(float x) {
    unsigned u = __float_as_uint(x);
    u = (u + 0x7FFFu + ((u >> 16) & 1u)) >> 16;
    return (unsigned short)u;
}
__device__ __forceinline__ float bf2f(unsigned short h) {
    return __uint_as_float(((unsigned)h) << 16);
}
__device__ __forceinline__ void split3(float x, unsigned short& a,
                                       unsigned short& b, unsigned short& c) {
    a = f2bf(x); float r = x - bf2f(a);
    b = f2bf(r); r -= bf2f(b);
    c = f2bf(r);
}
__device__ __forceinline__ void split2(float x, unsigned short& a,
                                       unsigned short& b) {
    a = f2bf(x);
    b = f2bf(x - bf2f(a));
}

__device__ __forceinline__ float wave_allsum(float v) {
#pragma unroll
    for (int o = 1; o < 64; o <<= 1) v += __shfl_xor(v, o, 64);
    return v;
}

// ---- k_gh: G = E@wa+ba (+ GT transposed store), H = E@wp+bp.
// 2048 blocks x 128 thr: one 16x16 tile per block, wave h owns K-half.
// G and H both 6-term compensated (H 6-term is mandatory: 3-term H shifts
// layer-1 E by ~2.5e-4 -> adjacency sign flips -> 2e-2 failures, r7).
template<int L0>
__global__ __launch_bounds__(128) void k_gh(
    const float* __restrict__ Ef,            // layer0 input (f32)
    const unsigned short* __restrict__ Epl,  // layer1 input planes
    const float* __restrict__ Wa, const float* __restrict__ ba,
    const float* __restrict__ Wp, const float* __restrict__ bp,
    float* __restrict__ G, float* __restrict__ GT, float* __restrict__ H)
{
    __shared__ f32x4 part[64];
    int bid = blockIdx.x;
    int m = bid >> 10, b = (bid >> 8) & 3, t = bid & 255;
    int tm = t >> 4, tn = t & 15;
    const float* W = m ? Wp : Wa;
    const float* bias = m ? bp : ba;
    float* C = (m ? H : G) + b * MAT;
    int tid = threadIdx.x, h = tid >> 6, lane = tid & 63;
    int l15 = lane & 15, lk = (lane >> 4) * 8, lk4 = lane >> 4;

    f32x4 acc = 0.0f;
    int arow = b * MAT + (tm * 16 + l15) * NN;
    int col = tn * 16 + l15;

    const int TP[6] = {0, 0, 1, 0, 1, 2}, TQ[6] = {0, 1, 0, 2, 1, 0};
#pragma unroll
    for (int ks = 0; ks < 4; ++ks) {
        int kb = h * 128 + ks * 32 + lk;
        U8 aE[3], wv[3];
        if (L0) {
            f32x4 e0 = *(const f32x4*)&Ef[arow + kb];
            f32x4 e1 = *(const f32x4*)&Ef[arow + kb + 4];
#pragma unroll
            for (int i = 0; i < 4; ++i) {
                split3(e0[i], aE[0].u[i], aE[1].u[i], aE[2].u[i]);
                split3(e1[i], aE[0].u[i + 4], aE[1].u[i + 4], aE[2].u[i + 4]);
            }
        } else {
#pragma unroll
            for (int pp = 0; pp < 3; ++pp)
                aE[pp].v = *(const bf16x8*)&Epl[pp * BMAT + arow + kb];
        }
#pragma unroll
        for (int kk = 0; kk < 8; ++kk) {
            float wf = W[(kb + kk) * NN + col];
            split3(wf, wv[0].u[kk], wv[1].u[kk], wv[2].u[kk]);
        }
#pragma unroll
        for (int t6 = 0; t6 < 6; ++t6)
            MFMA(acc, aE[TP[t6]].v, wv[TQ[t6]].v);
    }
    if (h == 1) part[lane] = acc;
    __syncthreads();
    if (h == 0) {
        f32x4 hi = part[lane];
        float bv = bias[col];
        f32x4 tv;
#pragma unroll
        for (int r = 0; r < 4; ++r) tv[r] = (acc[r] + hi[r]) + bv;
#pragma unroll
        for (int r = 0; r < 4; ++r)
            C[(tm * 16 + lk4 * 4 + r) * NN + col] = tv[r];
        if (m == 0)
            *(f32x4*)&GT[b * MAT + col * NN + tm * 16 + lk4 * 4] = tv;
    }
}

// ---- k_fsP: fused prep + D/N GEMM pair + divide/fallback + symmetrize.
// grid (136, NB) x 512: wave w -> side=w>>2, quarter=w&3 (64 K-cols each).
// eL/eH 2-split (D/N rel err ~2^-18, all-positive sums, no cancellation;
// cannot flip adjacency -- that depends only on 6-term G).
template<int FINAL>
__global__ __launch_bounds__(512) void k_fsP(
    const float* __restrict__ G, const float* __restrict__ GT,
    const float* __restrict__ H, const float* __restrict__ ae,
    unsigned short* __restrict__ Epl, float* __restrict__ out)
{
    __shared__ float Fs[2][16 * 17];
    __shared__ float lst[2][4][16], hst[2][4][16], cst[2][4][16];
    __shared__ f32x4 pD[8][64], pN[8][64];
    int b = blockIdx.y;
    int ti = 0, rem = blockIdx.x;
    while (rem >= 16 - ti) { rem -= 16 - ti; ++ti; }
    int tj = ti + rem;
    int t = threadIdx.x, w = t >> 6, lane = t & 63, l15 = lane & 15, q = lane >> 4;
    int side = w >> 2, quar = w & 3;
    int R = side ? tj : ti, C = side ? ti : tj;

    // S = sum(ae): per-wave, identical deterministic order in every wave
    float sv = 0.f;
#pragma unroll
    for (int k = 0; k < 8; ++k) sv += ae[lane + 64 * k];
    float S = wave_allsum(sv);

    // H prep: R-tile rows, this wave's K-quarter (cols quar*64 + it*32 + q*8)
    float hrow[2][8];
    int hbase = b * MAT + (R * 16 + l15) * NN + quar * 64;
    float lmax = -3.4e38f, hsum = 0.f;
#pragma unroll
    for (int it = 0; it < 2; ++it) {
        f32x4 h0 = *(const f32x4*)&H[hbase + it * 32 + q * 8];
        f32x4 h1 = *(const f32x4*)&H[hbase + it * 32 + q * 8 + 4];
#pragma unroll
        for (int i = 0; i < 4; ++i) { hrow[it][i] = h0[i]; hrow[it][i + 4] = h1[i]; }
#pragma unroll
        for (int i = 0; i < 8; ++i) {
            float x = S * hrow[it][i];
            float L = (x > 0.f) ? x : ALPHA * x;
            lmax = fmaxf(lmax, L);
            hsum += hrow[it][i];
        }
    }
    lmax = fmaxf(lmax, __shfl_xor(lmax, 16, 64));
    lmax = fmaxf(lmax, __shfl_xor(lmax, 32, 64));
    hsum += __shfl_xor(hsum, 16, 64);
    hsum += __shfl_xor(hsum, 32, 64);
    if (q == 0) { lst[side][quar][l15] = lmax; hst[side][quar][l15] = hsum; }

    // adjacency frags + cnt partial for C-rows, this wave's K-quarter
    float cntp = 0.f;
    bf16x8 adjf[2];
    int gbase = b * MAT + (C * 16 + l15) * NN + quar * 64;
#pragma unroll
    for (int it = 0; it < 2; ++it) {
        f32x4 g0 = *(const f32x4*)&G[gbase + it * 32 + q * 8];
        f32x4 g1 = *(const f32x4*)&G[gbase + it * 32 + q * 8 + 4];
        f32x4 t0 = *(const f32x4*)&GT[gbase + it * 32 + q * 8];
        f32x4 t1 = *(const f32x4*)&GT[gbase + it * 32 + q * 8 + 4];
        U8 a_;
#pragma unroll
        for (int i = 0; i < 4; ++i) {
            bool b0 = (g0[i] + t0[i] > 0.f);
            bool b1 = (g1[i] + t1[i] > 0.f);
            cntp += (b0 ? 1.f : 0.f) + (b1 ? 1.f : 0.f);
            a_.u[i] = b0 ? 0x3F80 : 0;
            a_.u[i + 4] = b1 ? 0x3F80 : 0;
        }
        adjf[it] = a_.v;
    }
    cntp += __shfl_xor(cntp, 16, 64);
    cntp += __shfl_xor(cntp, 32, 64);
    if (q == 0) cst[side][quar][l15] = cntp;
    __syncthreads();

    // combined exact row max for this side
    float lmaxC = fmaxf(fmaxf(lst[side][0][l15], lst[side][1][l15]),
                        fmaxf(lst[side][2][l15], lst[side][3][l15]));

    // D/N MFMA with on-the-fly eL/eH 2-split fragments (quarter-K partials)
    f32x4 aD = 0.f, aN = 0.f;
#pragma unroll
    for (int it = 0; it < 2; ++it) {
        U8 e0, e1, q0, q1;
#pragma unroll
        for (int i = 0; i < 8; ++i) {
            float x = S * hrow[it][i];
            float L = (x > 0.f) ? x : ALPHA * x;
            float e = __expf(L - lmaxC);
            float eh = e * hrow[it][i];
            split2(e,  e0.u[i], e1.u[i]);
            split2(eh, q0.u[i], q1.u[i]);
        }
        MFMA(aD, e0.v, adjf[it]); MFMA(aD, e1.v, adjf[it]);
        MFMA(aN, q0.v, adjf[it]); MFMA(aN, q1.v, adjf[it]);
    }
    pD[w][lane] = aD;
    pN[w][lane] = aN;
    __syncthreads();

    // epilogue on quarter-0 waves (one per side)
    float F[4] = {0.f, 0.f, 0.f, 0.f};
    if (quar == 0) {
        float cntC = ((cst[side][0][l15] + cst[side][1][l15]) +
                      cst[side][2][l15]) + cst[side][3][l15];
#pragma unroll
        for (int r = 0; r < 4; ++r) {
            int m = q * 4 + r;
            float dv = ((pD[4*side][lane][r] + pD[4*side+1][lane][r]) +
                        pD[4*side+2][lane][r]) + pD[4*side+3][lane][r];
            float nv = ((pN[4*side][lane][r] + pN[4*side+1][lane][r]) +
                        pN[4*side+2][lane][r]) + pN[4*side+3][lane][r];
            float rsv = (((hst[side][0][m] + hst[side][1][m]) +
                          hst[side][2][m]) + hst[side][3][m]) * (1.f / 256.f);
            F[r] = (cntC > 0.5f) ? nv / dv : rsv;
            Fs[side][m * 17 + l15] = F[r];
        }
    }
    __syncthreads();
    if (quar == 0) {
#pragma unroll
        for (int r = 0; r < 4; ++r) {
            int m = q * 4 + r;
            float e = 0.5f * (F[r] + Fs[1 ^ side][l15 * 17 + m]);
            int idx = b * MAT + (R * 16 + m) * NN + C * 16 + l15;
            if (FINAL) {
                float tv = tanhf(e);
                out[idx] = tv; out[BMAT + idx] = tv;
            } else {
                unsigned short s0, s1, s2;
                split3(e, s0, s1, s2);
                Epl[idx] = s0; Epl[BMAT + idx] = s1; Epl[2 * BMAT + idx] = s2;
            }
        }
    }
}

extern "C" void kernel_launch(void* const* d_in, const int* in_sizes, int n_in,
                              void* d_out, int out_size, void* d_ws, size_t ws_size,
                              hipStream_t stream) {
    const float* edges = (const float*)d_in[1];
    const float* wp[2] = {(const float*)d_in[7],  (const float*)d_in[17]};
    const float* bp[2] = {(const float*)d_in[8],  (const float*)d_in[18]};
    const float* ae[2] = {(const float*)d_in[9],  (const float*)d_in[19]};
    const float* wa[2] = {(const float*)d_in[10], (const float*)d_in[20]};
    const float* ba[2] = {(const float*)d_in[11], (const float*)d_in[21]};
    float* out = (float*)d_out;

    // ws layout (~4.5 MB)
    unsigned short* EplB = (unsigned short*)d_ws;    // 3 planes (layer-1 input)
    float* G  = (float*)(EplB + 3 * BMAT);           // 1MB
    float* GT = G + BMAT;                            // 1MB
    float* H  = GT + BMAT;                           // 1MB

    k_gh<1><<<2048, 128, 0, stream>>>(edges, nullptr, wa[0], ba[0], wp[0], bp[0],
                                      G, GT, H);
    k_fsP<0><<<dim3(136, NB), 512, 0, stream>>>(G, GT, H, ae[0], EplB, nullptr);
    k_gh<0><<<2048, 128, 0, stream>>>(nullptr, EplB, wa[1], ba[1], wp[1], bp[1],
                                      G, GT, H);
    k_fsP<1><<<dim3(136, NB), 512, 0, stream>>>(G, GT, H, ae[1], nullptr, out);
}

// Round 15
// 49.345 us; speedup vs baseline: 2.7802x; 1.0866x over previous
//
#include <hip/hip_runtime.h>
#include <math.h>

#define NB 4
#define NN 256
#define MAT (NN*NN)      // 65536
#define BMAT (NB*MAT)    // 262144
#define ALPHA 0.2f

typedef __attribute__((ext_vector_type(8))) __bf16 bf16x8;
typedef __attribute__((ext_vector_type(4))) float f32x4;

union U8 { bf16x8 v; unsigned short u[8]; };

#define MFMA(acc, A, B) acc = __builtin_amdgcn_mfma_f32_16x16x32_bf16(A, B, acc, 0, 0, 0)

// native f32->bf16 RNE conversion (single HW instr; same rounding as the
// integer bit-trick used in prior rounds -> bit-identical planes)
__device__ __forceinline__ unsigned short f2bf(float x) {
    __bf16 h = (__bf16)x;
    return __builtin_bit_cast(unsigned short, h);
}
__device__ __forceinline__ float bf2f(unsigned short h) {
    return __uint_as_float(((unsigned)h) << 16);
}
__device__ __forceinline__ void split3(float x, unsigned short& a,
                                       unsigned short& b, unsigned short& c) {
    a = f2bf(x); float r = x - bf2f(a);
    b = f2bf(r); r -= bf2f(b);
    c = f2bf(r);
}
__device__ __forceinline__ void split2(float x, unsigned short& a,
                                       unsigned short& b) {
    a = f2bf(x);
    b = f2bf(x - bf2f(a));
}

__device__ __forceinline__ float wave_allsum(float v) {
#pragma unroll
    for (int o = 1; o < 64; o <<= 1) v += __shfl_xor(v, o, 64);
    return v;
}

// ---- k_gh: G = E@wa+ba (+ GT transposed store), H = E@wp+bp.
// 2048 blocks x 128 thr: one 16x16 tile per block, wave h owns K-half.
// G and H both 6-term compensated (H 6-term is mandatory: 3-term H shifts
// layer-1 E by ~2.5e-4 -> adjacency sign flips -> 2e-2 failures, r7).
template<int L0>
__global__ __launch_bounds__(128) void k_gh(
    const float* __restrict__ Ef,            // layer0 input (f32)
    const unsigned short* __restrict__ Epl,  // layer1 input planes
    const float* __restrict__ Wa, const float* __restrict__ ba,
    const float* __restrict__ Wp, const float* __restrict__ bp,
    float* __restrict__ G, float* __restrict__ GT, float* __restrict__ H)
{
    __shared__ f32x4 part[64];
    int bid = blockIdx.x;
    int m = bid >> 10, b = (bid >> 8) & 3, t = bid & 255;
    int tm = t >> 4, tn = t & 15;
    const float* W = m ? Wp : Wa;
    const float* bias = m ? bp : ba;
    float* C = (m ? H : G) + b * MAT;
    int tid = threadIdx.x, h = tid >> 6, lane = tid & 63;
    int l15 = lane & 15, lk = (lane >> 4) * 8, lk4 = lane >> 4;

    f32x4 acc = 0.0f;
    int arow = b * MAT + (tm * 16 + l15) * NN;
    int col = tn * 16 + l15;

    const int TP[6] = {0, 0, 1, 0, 1, 2}, TQ[6] = {0, 1, 0, 2, 1, 0};
#pragma unroll
    for (int ks = 0; ks < 4; ++ks) {
        int kb = h * 128 + ks * 32 + lk;
        U8 aE[3], wv[3];
        if (L0) {
            f32x4 e0 = *(const f32x4*)&Ef[arow + kb];
            f32x4 e1 = *(const f32x4*)&Ef[arow + kb + 4];
#pragma unroll
            for (int i = 0; i < 4; ++i) {
                split3(e0[i], aE[0].u[i], aE[1].u[i], aE[2].u[i]);
                split3(e1[i], aE[0].u[i + 4], aE[1].u[i + 4], aE[2].u[i + 4]);
            }
        } else {
#pragma unroll
            for (int pp = 0; pp < 3; ++pp)
                aE[pp].v = *(const bf16x8*)&Epl[pp * BMAT + arow + kb];
        }
#pragma unroll
        for (int kk = 0; kk < 8; ++kk) {
            float wf = W[(kb + kk) * NN + col];
            split3(wf, wv[0].u[kk], wv[1].u[kk], wv[2].u[kk]);
        }
#pragma unroll
        for (int t6 = 0; t6 < 6; ++t6)
            MFMA(acc, aE[TP[t6]].v, wv[TQ[t6]].v);
    }
    if (h == 1) part[lane] = acc;
    __syncthreads();
    if (h == 0) {
        f32x4 hi = part[lane];
        float bv = bias[col];
        f32x4 tv;
#pragma unroll
        for (int r = 0; r < 4; ++r) tv[r] = (acc[r] + hi[r]) + bv;
#pragma unroll
        for (int r = 0; r < 4; ++r)
            C[(tm * 16 + lk4 * 4 + r) * NN + col] = tv[r];
        if (m == 0)
            *(f32x4*)&GT[b * MAT + col * NN + tm * 16 + lk4 * 4] = tv;
    }
}

// ---- k_fsP: fused prep + D/N GEMM pair + divide/fallback + symmetrize.
// grid (136, NB) x 512: wave w -> side=w>>2, quarter=w&3 (64 K-cols each).
// No max-subtraction (L in [-O(10),O(10)], exp safely in f32; N/D ratio is
// shift-invariant) -> no pre-MFMA cross-wave dependency, single barrier.
// eL/eH 2-split (all-positive sums, no cancellation; adjacency depends only
// on 6-term G).
template<int FINAL>
__global__ __launch_bounds__(512) void k_fsP(
    const float* __restrict__ G, const float* __restrict__ GT,
    const float* __restrict__ H, const float* __restrict__ ae,
    unsigned short* __restrict__ Epl, float* __restrict__ out)
{
    __shared__ float Fs[2][16 * 17];
    __shared__ float hst[2][4][16], cst[2][4][16];
    __shared__ f32x4 pD[8][64], pN[8][64];
    int b = blockIdx.y;
    int ti = 0, rem = blockIdx.x;
    while (rem >= 16 - ti) { rem -= 16 - ti; ++ti; }
    int tj = ti + rem;
    int t = threadIdx.x, w = t >> 6, lane = t & 63, l15 = lane & 15, q = lane >> 4;
    int side = w >> 2, quar = w & 3;
    int R = side ? tj : ti, C = side ? ti : tj;

    // S = sum(ae): per-wave, identical deterministic order in every wave
    float sv = 0.f;
#pragma unroll
    for (int k = 0; k < 8; ++k) sv += ae[lane + 64 * k];
    float S = wave_allsum(sv);

    // H rows for R-tile, this wave's K-quarter (cols quar*64 + it*32 + q*8)
    float hrow[2][8];
    int hbase = b * MAT + (R * 16 + l15) * NN + quar * 64;
    float hsum = 0.f;
#pragma unroll
    for (int it = 0; it < 2; ++it) {
        f32x4 h0 = *(const f32x4*)&H[hbase + it * 32 + q * 8];
        f32x4 h1 = *(const f32x4*)&H[hbase + it * 32 + q * 8 + 4];
#pragma unroll
        for (int i = 0; i < 4; ++i) { hrow[it][i] = h0[i]; hrow[it][i + 4] = h1[i]; }
#pragma unroll
        for (int i = 0; i < 8; ++i) hsum += hrow[it][i];
    }
    hsum += __shfl_xor(hsum, 16, 64);
    hsum += __shfl_xor(hsum, 32, 64);
    if (q == 0) hst[side][quar][l15] = hsum;

    // adjacency frags + cnt partial for C-rows, this wave's K-quarter
    float cntp = 0.f;
    bf16x8 adjf[2];
    int gbase = b * MAT + (C * 16 + l15) * NN + quar * 64;
#pragma unroll
    for (int it = 0; it < 2; ++it) {
        f32x4 g0 = *(const f32x4*)&G[gbase + it * 32 + q * 8];
        f32x4 g1 = *(const f32x4*)&G[gbase + it * 32 + q * 8 + 4];
        f32x4 t0 = *(const f32x4*)&GT[gbase + it * 32 + q * 8];
        f32x4 t1 = *(const f32x4*)&GT[gbase + it * 32 + q * 8 + 4];
        U8 a_;
#pragma unroll
        for (int i = 0; i < 4; ++i) {
            bool b0 = (g0[i] + t0[i] > 0.f);
            bool b1 = (g1[i] + t1[i] > 0.f);
            cntp += (b0 ? 1.f : 0.f) + (b1 ? 1.f : 0.f);
            a_.u[i] = b0 ? 0x3F80 : 0;
            a_.u[i + 4] = b1 ? 0x3F80 : 0;
        }
        adjf[it] = a_.v;
    }
    cntp += __shfl_xor(cntp, 16, 64);
    cntp += __shfl_xor(cntp, 32, 64);
    if (q == 0) cst[side][quar][l15] = cntp;

    // D/N MFMA with on-the-fly eL/eH 2-split fragments (quarter-K partials)
    f32x4 aD = 0.f, aN = 0.f;
#pragma unroll
    for (int it = 0; it < 2; ++it) {
        U8 e0, e1, q0, q1;
#pragma unroll
        for (int i = 0; i < 8; ++i) {
            float x = S * hrow[it][i];
            float L = (x > 0.f) ? x : ALPHA * x;
            float e = __expf(L);
            float eh = e * hrow[it][i];
            split2(e,  e0.u[i], e1.u[i]);
            split2(eh, q0.u[i], q1.u[i]);
        }
        MFMA(aD, e0.v, adjf[it]); MFMA(aD, e1.v, adjf[it]);
        MFMA(aN, q0.v, adjf[it]); MFMA(aN, q1.v, adjf[it]);
    }
    pD[w][lane] = aD;
    pN[w][lane] = aN;
    __syncthreads();

    // epilogue on quarter-0 waves (one per side)
    float F[4] = {0.f, 0.f, 0.f, 0.f};
    if (quar == 0) {
        float cntC = ((cst[side][0][l15] + cst[side][1][l15]) +
                      cst[side][2][l15]) + cst[side][3][l15];
#pragma unroll
        for (int r = 0; r < 4; ++r) {
            int m = q * 4 + r;
            float dv = ((pD[4*side][lane][r] + pD[4*side+1][lane][r]) +
                        pD[4*side+2][lane][r]) + pD[4*side+3][lane][r];
            float nv = ((pN[4*side][lane][r] + pN[4*side+1][lane][r]) +
                        pN[4*side+2][lane][r]) + pN[4*side+3][lane][r];
            float rsv = (((hst[side][0][m] + hst[side][1][m]) +
                          hst[side][2][m]) + hst[side][3][m]) * (1.f / 256.f);
            F[r] = (cntC > 0.5f) ? nv / dv : rsv;
            Fs[side][m * 17 + l15] = F[r];
        }
    }
    __syncthreads();
    if (quar == 0) {
#pragma unroll
        for (int r = 0; r < 4; ++r) {
            int m = q * 4 + r;
            float e = 0.5f * (F[r] + Fs[1 ^ side][l15 * 17 + m]);
            int idx = b * MAT + (R * 16 + m) * NN + C * 16 + l15;
            if (FINAL) {
                float tv = tanhf(e);
                out[idx] = tv; out[BMAT + idx] = tv;
            } else {
                unsigned short s0, s1, s2;
                split3(e, s0, s1, s2);
                Epl[idx] = s0; Epl[BMAT + idx] = s1; Epl[2 * BMAT + idx] = s2;
            }
        }
    }
}

extern "C" void kernel_launch(void* const* d_in, const int* in_sizes, int n_in,
                              void* d_out, int out_size, void* d_ws, size_t ws_size,
                              hipStream_t stream) {
    const float* edges = (const float*)d_in[1];
    const float* wp[2] = {(const float*)d_in[7],  (const float*)d_in[17]};
    const float* bp[2] = {(const float*)d_in[8],  (const float*)d_in[18]};
    const float* ae[2] = {(const float*)d_in[9],  (const float*)d_in[19]};
    const float* wa[2] = {(const float*)d_in[10], (const float*)d_in[20]};
    const float* ba[2] = {(const float*)d_in[11], (const float*)d_in[21]};
    float* out = (float*)d_out;

    // ws layout (~4.5 MB)
    unsigned short* EplB = (unsigned short*)d_ws;    // 3 planes (layer-1 input)
    float* G  = (float*)(EplB + 3 * BMAT);           // 1MB
    float* GT = G + BMAT;                            // 1MB
    float* H  = GT + BMAT;                           // 1MB

    k_gh<1><<<2048, 128, 0, stream>>>(edges, nullptr, wa[0], ba[0], wp[0], bp[0],
                                      G, GT, H);
    k_fsP<0><<<dim3(136, NB), 512, 0, stream>>>(G, GT, H, ae[0], EplB, nullptr);
    k_gh<0><<<2048, 128, 0, stream>>>(nullptr, EplB, wa[1], ba[1], wp[1], bp[1],
                                      G, GT, H);
    k_fsP<1><<<dim3(136, NB), 512, 0, stream>>>(G, GT, H, ae[1], nullptr, out);
}